// Round 6
// baseline (9568.697 us; speedup 1.0000x reference)
//
#include <hip/hip_runtime.h>
#include <hip/hip_bf16.h>
#include <float.h>

#define NN 3072
#define MM 3072
#define DD 64
#define KK 8
#define NPROB 24

constexpr float C_EPS   = 0.0025f;   // blur^2
constexpr int   C_NITER = 30;
constexpr float LOG2E = 1.4426950408889634f;
constexpr float LN2F  = 0.6931471805599453f;
constexpr float L2_SCAL2 = -0.6438561897747247f;   // log2(0.64)

__device__ __forceinline__ float ex2(float x){ return __builtin_amdgcn_exp2f(x); }
__device__ __forceinline__ float lg2(float x){ return __builtin_amdgcn_logf(x); }

// workspace layout in 4-byte units
#define U_FILL 0        // 8 floats  (zeroed by memset)
#define U_MAXC 8        // 4 uints   (zeroed)
#define U_CNTX 12       // 8 int
#define U_CNTY 20       // 8 int
#define U_POSX 28       // 8 int
#define U_POSY 36       // 8 int  -> memset covers [0,44)
#define U_OFFX 44       // 9 int
#define U_OFFY 53       // 9 int
#define U_PNX  64       // 24 int
#define U_PNY  88
#define U_PRB  112
#define U_PCB  136
#define U_PRS  160
#define U_PCS  184
#define U_PCOFF 208     // 25 int
#define U_PTOF  233     // 24 int  (C^T offsets; == PCOFF for symmetric xx/yy)
#define U_TOFF  257     // 25 int
#define U_XSQ  320      // 3072 float
#define U_YSQ  3392     // 3072 float
#define U_PRED 6464     // 3072 int
#define U_ROWS 9536     // 3072 int
#define U_COLS 12608    // 3072 int
#define U_SUBC 15680    // compact submatrices C, then appended C^T blocks (floats)

// ---------------- kernel 1: per-x-point: norms, argmin, softmax filling ----------------
__global__ __launch_bounds__(256) void k_prep_x(const float* __restrict__ x,
                                                const float* __restrict__ cc,
                                                float* wf, int* wi) {
    __shared__ __align__(16) float c_s[KK][DD];
    __shared__ float csq_s[KK];
    __shared__ float fpart[KK];
    int tid = threadIdx.x;
    for (int e = tid; e < KK*DD; e += 256) c_s[e>>6][e&63] = cc[e];
    if (tid < KK) fpart[tid] = 0.f;
    __syncthreads();
    if (tid < KK) { float s=0.f; for (int d=0; d<DD; ++d){ float v=c_s[tid][d]; s+=v*v; } csq_s[tid]=s; }
    __syncthreads();
    int i = blockIdx.x*256 + tid;
    if (i < NN) {
        const float4* xr = (const float4*)(x + (size_t)i*DD);
        float4 xv[16];
        float xs = 0.f;
        #pragma unroll
        for (int q=0;q<16;++q){ xv[q]=xr[q];
            xs += xv[q].x*xv[q].x + xv[q].y*xv[q].y + xv[q].z*xv[q].z + xv[q].w*xv[q].w; }
        float dk[KK];
        #pragma unroll
        for (int k=0;k<KK;++k){
            const float4* cr = (const float4*)(&c_s[k][0]);
            float dot=0.f;
            #pragma unroll
            for (int q=0;q<16;++q){ float4 cv=cr[q];
                dot += xv[q].x*cv.x + xv[q].y*cv.y + xv[q].z*cv.z + xv[q].w*cv.w; }
            dk[k] = xs + csq_s[k] - 2.f*dot;
        }
        float dmin = dk[0]; int am=0;
        #pragma unroll
        for (int k=1;k<KK;++k){ if (dk[k] < dmin){ dmin=dk[k]; am=k; } }
        float se=0.f; float ek[KK];
        #pragma unroll
        for (int k=0;k<KK;++k){ ek[k] = ex2((dmin-dk[k])*LOG2E); se+=ek[k]; }
        float inv = 1.f/se;
        #pragma unroll
        for (int k=0;k<KK;++k) atomicAdd(&fpart[k], ek[k]*inv);
        wf[U_XSQ + i] = xs;
        wi[U_PRED + i] = am;
        atomicAdd(&wi[U_CNTX + am], 1);
    }
    __syncthreads();
    if (tid < KK) atomicAdd(&wf[U_FILL + tid], fpart[tid]);
}

// ---------------- kernel 2: per-target: norms + counts ----------------
__global__ __launch_bounds__(256) void k_prep_y(const float* __restrict__ y,
                                                const int* __restrict__ predt,
                                                float* wf, int* wi) {
    int j = blockIdx.x*256 + threadIdx.x;
    if (j < MM) {
        const float4* yr = (const float4*)(y + (size_t)j*DD);
        float s=0.f;
        #pragma unroll
        for (int q=0;q<16;++q){ float4 v=yr[q]; s += v.x*v.x+v.y*v.y+v.z*v.z+v.w*v.w; }
        wf[U_YSQ + j] = s;
        atomicAdd(&wi[U_CNTY + predt[j]], 1);
    }
}

// ---------------- kernel 3: prefix sums, problem tables, loss_fil ----------------
__global__ void k_offsets(const float* __restrict__ ftarg, float* wf, int* wi, float* out) {
    if (threadIdx.x != 0) return;
    int offx=0, offy=0;
    wi[U_OFFX]=0; wi[U_OFFY]=0;
    for (int k=0;k<KK;++k){
        offx += wi[U_CNTX+k]; wi[U_OFFX+k+1]=offx;
        offy += wi[U_CNTY+k]; wi[U_OFFY+k+1]=offy;
    }
    int co=0, to=0;
    for (int k=0;k<KK;++k){
        int cx=wi[U_CNTX+k], cy=wi[U_CNTY+k];
        bool val = (cx>0)&&(cy>0);
        for (int t=0;t<3;++t){
            int p=k*3+t;
            int nx = val ? (t==2?cy:cx) : 0;
            int ny = val ? (t==1?cx:cy) : 0;
            wi[U_PNX+p]=nx; wi[U_PNY+p]=ny;
            wi[U_PRB+p] = (t==2)? wi[U_OFFY+k] : wi[U_OFFX+k];
            wi[U_PCB+p] = (t==1)? wi[U_OFFX+k] : wi[U_OFFY+k];
            wi[U_PRS+p] = (t==2)?1:0;
            wi[U_PCS+p] = (t==1)?0:1;
            wi[U_PCOFF+p]=co; co += nx*ny;
            wi[U_TOFF+p]=to; to += ((nx+31)>>5)*((ny+31)>>5);
        }
    }
    wi[U_PCOFF+NPROB]=co; wi[U_TOFF+NPROB]=to;
    // C^T blocks appended after all C; xx/yy are symmetric so CT == C
    int cto = co;
    for (int p=0;p<NPROB;++p){
        if (p%3 == 0){ wi[U_PTOF+p] = cto; cto += wi[U_PNX+p]*wi[U_PNY+p]; }
        else         { wi[U_PTOF+p] = wi[U_PCOFF+p]; }
    }
    float lf=0.f;
    for (int k=0;k<KK;++k){ float fx = wf[U_FILL+k]/(float)NN; float dd = fx - ftarg[k]; lf += dd*dd; }
    out[0] = lf/(float)KK;
}

// ---------------- kernel 4: scatter compact index lists ----------------
__global__ __launch_bounds__(256) void k_scatter(const int* __restrict__ predt, int* wi) {
    int b = blockIdx.x;
    if (b < 12) {
        int i = b*256 + threadIdx.x;
        if (i < NN){ int k = wi[U_PRED+i]; int p = atomicAdd(&wi[U_POSX+k],1);
                     wi[U_ROWS + wi[U_OFFX+k] + p] = i; }
    } else {
        int j = (b-12)*256 + threadIdx.x;
        if (j < MM){ int k = predt[j]; int p = atomicAdd(&wi[U_POSY+k],1);
                     wi[U_COLS + wi[U_OFFY+k] + p] = j; }
    }
}

// ---------------- kernel 5: exact max over full cost matrices (tiled) ----------------
__global__ __launch_bounds__(256) void k_maxmat(const float* __restrict__ x,
                                                const float* __restrict__ y,
                                                float* wf, int* wi) {
    int z = blockIdx.z;
    const float* A = (z==2)? y : x;
    const float* B = (z==0)? y : ((z==1)? x : y);
    int aqo = (z==2)? U_YSQ : U_XSQ;
    int bqo = (z==1)? U_XSQ : U_YSQ;
    __shared__ float la[64][65];
    __shared__ float lb[64][65];
    __shared__ float laq[64], lbq[64];
    __shared__ float wred[4];
    int tid = threadIdx.x;
    int i0 = blockIdx.y*64, j0 = blockIdx.x*64;
    #pragma unroll
    for (int q=0;q<4;++q){
        int idx4 = tid + q*256;
        int r = idx4>>4; int c = (idx4&15)<<2;
        float4 va = *(const float4*)(A + (size_t)(i0+r)*DD + c);
        la[r][c]=va.x; la[r][c+1]=va.y; la[r][c+2]=va.z; la[r][c+3]=va.w;
        float4 vb = *(const float4*)(B + (size_t)(j0+r)*DD + c);
        lb[r][c]=vb.x; lb[r][c+1]=vb.y; lb[r][c+2]=vb.z; lb[r][c+3]=vb.w;
    }
    if (tid < 64) { laq[tid]=wf[aqo+i0+tid]; lbq[tid]=wf[bqo+j0+tid]; }
    __syncthreads();
    int r0 = (tid>>4)<<2, c0 = (tid&15)<<2;
    float acc[4][4] = {};
    for (int d=0; d<DD; ++d){
        float av[4], bv[4];
        #pragma unroll
        for (int a=0;a<4;++a){ av[a]=la[r0+a][d]; bv[a]=lb[c0+a][d]; }
        #pragma unroll
        for (int a=0;a<4;++a)
            #pragma unroll
            for (int b2=0;b2<4;++b2) acc[a][b2] += av[a]*bv[b2];
    }
    float m = 0.f;
    #pragma unroll
    for (int a=0;a<4;++a)
        #pragma unroll
        for (int b2=0;b2<4;++b2){
            float cst = 0.5f*(laq[r0+a]+lbq[c0+b2]) - acc[a][b2];
            m = fmaxf(m, cst);
        }
    #pragma unroll
    for (int o=32;o;o>>=1) m = fmaxf(m, __shfl_xor(m,o));
    int wid = tid>>6;
    if ((tid&63)==0) wred[wid]=m;
    __syncthreads();
    if (tid==0){
        float mm = fmaxf(fmaxf(wred[0],wred[1]),fmaxf(wred[2],wred[3]));
        atomicMax((unsigned int*)&wi[U_MAXC+z], __float_as_uint(mm));
    }
}

// ---------------- kernel 6: gather compact cost submatrices (+ C^T for xy) ----------------
__global__ __launch_bounds__(256) void k_gather(const float* __restrict__ x,
                                                const float* __restrict__ y,
                                                float* wf, int* wi) {
    __shared__ float xs_[32][65], ys_[32][65];
    __shared__ float cs_[32][33];
    __shared__ float rq[32], cq[32];
    __shared__ int toff_s[NPROB+1];
    int tid = threadIdx.x;
    if (tid <= NPROB) toff_s[tid] = wi[U_TOFF+tid];
    __syncthreads();
    int total = toff_s[NPROB];
    for (int tix = blockIdx.x; tix < total; tix += gridDim.x){
        int p = 0;
        while (toff_s[p+1] <= tix) ++p;
        int nx = wi[U_PNX+p], ny = wi[U_PNY+p];
        int tpr = (ny+31)>>5;
        int loc = tix - toff_s[p];
        int i0 = (loc/tpr)<<5, j0 = (loc%tpr)<<5;
        int rbase = wi[U_PRB+p], cbase = wi[U_PCB+p];
        int rs = wi[U_PRS+p], cs = wi[U_PCS+p];
        const float* rsrc = rs? y : x;
        const float* csrc = cs? y : x;
        const int* rlist = wi + (rs? U_COLS : U_ROWS);
        const int* clist = wi + (cs? U_COLS : U_ROWS);
        int rqo = rs? U_YSQ : U_XSQ;
        int cqo = cs? U_YSQ : U_XSQ;
        size_t coff = (size_t)wi[U_PCOFF+p];
        #pragma unroll
        for (int q=0;q<2;++q){
            int idx4 = tid + q*256;      // 0..511
            int r = idx4>>4, c = (idx4&15)<<2;
            if (i0 + r < nx){
                int gi = rlist[rbase + i0 + r];
                float4 v = *(const float4*)(rsrc + (size_t)gi*DD + c);
                xs_[r][c]=v.x; xs_[r][c+1]=v.y; xs_[r][c+2]=v.z; xs_[r][c+3]=v.w;
                if (c==0) rq[r] = wf[rqo + gi];
            }
            if (j0 + r < ny){
                int gj = clist[cbase + j0 + r];
                float4 v = *(const float4*)(csrc + (size_t)gj*DD + c);
                ys_[r][c]=v.x; ys_[r][c+1]=v.y; ys_[r][c+2]=v.z; ys_[r][c+3]=v.w;
                if (c==0) cq[r] = wf[cqo + gj];
            }
        }
        __syncthreads();
        int r = tid>>3, cb = (tid&7)<<2;
        float cv[4] = {0.f,0.f,0.f,0.f};
        if (i0 + r < nx){
            float acc[4] = {0.f,0.f,0.f,0.f};
            for (int d=0; d<DD; ++d){
                float xv = xs_[r][d];
                #pragma unroll
                for (int q=0;q<4;++q) acc[q] += xv*ys_[cb+q][d];
            }
            float* dst = wf + U_SUBC + coff + (size_t)(i0+r)*ny + j0;
            #pragma unroll
            for (int q=0;q<4;++q){
                int j = cb+q;
                cv[q] = 0.5f*(rq[r]+cq[j]) - acc[q];
                if (j0 + j < ny) dst[j] = cv[q];
            }
        }
        if (p%3 == 0){
            // stash tile, write transposed (coalesced along nx) into CT
            #pragma unroll
            for (int q=0;q<4;++q) cs_[r][cb+q] = cv[q];
            __syncthreads();
            if (j0 + r < ny){
                float* dT = wf + U_SUBC + (size_t)wi[U_PTOF+p] + (size_t)(j0+r)*nx + i0;
                #pragma unroll
                for (int q=0;q<4;++q){
                    int ii = cb+q;
                    if (i0 + ii < nx) dT[ii] = cs_[ii][r];
                }
            }
        }
        __syncthreads();
    }
}

// ---------------- kernel 7: one block per OT problem; whole sinkhorn in-block ----------------
// Potentials f,g live in LDS; phases separated by __syncthreads only (no global sync).
// Stabilizer trick: use previous iteration's true row-max (rescaled by eps-ratio) as the
// LSE stabilizer; track the true max with an independent fmax chain for the next iteration.
// This takes exp2 OFF the dependency chain and costs 1 exp per element.
__global__ __launch_bounds__(1024) void k_sink(float* wf, int* wi, float* out) {
    int p = blockIdx.x;
    int nx = wi[U_PNX+p], ny = wi[U_PNY+p];
    if (nx <= 0 || ny <= 0) return;
    int tid = threadIdx.x, w = tid>>6, lane = tid&63;
    float eps0 = fmaxf(__uint_as_float((unsigned)wi[U_MAXC + (p%3)]), C_EPS);
    const float* C  = wf + U_SUBC + (size_t)wi[U_PCOFF+p];
    const float* CT = wf + U_SUBC + (size_t)wi[U_PTOF+p];
    float l2ny = lg2((float)ny), l2nx = lg2((float)nx);
    __shared__ float fl[3072], gl[3072], mf[3072], mg[3072], gs[3072];
    __shared__ float sacc[2];
    for (int j=tid; j<ny; j+=1024){ gl[j]=0.f; mg[j]=0.f; }
    for (int i=tid; i<nx; i+=1024){ mf[i]=0.f; }
    if (tid < 2) sacc[tid]=0.f;
    float prev_ie2 = 1.f;

    for (int it=0; it<C_NITER; ++it){
        float eps = fmaxf(eps0*ex2((float)it*L2_SCAL2), C_EPS);
        float ie2 = LOG2E/eps, neL = -eps*LN2F;
        float r = (it==0)? 0.f : ie2/prev_ie2;
        prev_ie2 = ie2;
        __syncthreads();                       // gl ready / gs free
        for (int j=tid; j<ny; j+=1024) gs[j] = gl[j]*ie2;
        __syncthreads();
        // ---- f-phase: wave per row of C (coalesced), estimate-stabilized LSE ----
        for (int i=w; i<nx; i+=16){
            const float* Cr = C + (size_t)i*ny;
            float mrow = mf[i]*r;
            float S = 0.f, dmax = -FLT_MAX;
            for (int j=lane; j<ny; j+=64){
                float d = fmaf(Cr[j], -ie2, gs[j]) - mrow;
                dmax = fmaxf(dmax, d);
                S += ex2(fminf(d, 80.f));
            }
            #pragma unroll
            for (int o=32;o;o>>=1){ S += __shfl_xor(S,o); dmax = fmaxf(dmax, __shfl_xor(dmax,o)); }
            if (lane==0){ fl[i] = neL*(mrow + lg2(S) - l2ny); mf[i] = mrow + dmax; }
        }
        __syncthreads();                       // fl ready / gs free
        for (int i=tid; i<nx; i+=1024) gs[i] = fl[i]*ie2;
        __syncthreads();
        // ---- g-phase: wave per row of CT (coalesced) ----
        for (int j=w; j<ny; j+=16){
            const float* Tr = CT + (size_t)j*nx;
            float mrow = mg[j]*r;
            float S = 0.f, dmax = -FLT_MAX;
            for (int i=lane; i<nx; i+=64){
                float d = fmaf(Tr[i], -ie2, gs[i]) - mrow;
                dmax = fmaxf(dmax, d);
                S += ex2(fminf(d, 80.f));
            }
            #pragma unroll
            for (int o=32;o;o>>=1){ S += __shfl_xor(S,o); dmax = fmaxf(dmax, __shfl_xor(dmax,o)); }
            if (lane==0){ gl[j] = neL*(mrow + lg2(S) - l2nx); mg[j] = mrow + dmax; }
        }
    }
    // ---- final differentiable update at eps=EPS: f2 (accumulate), g2 (uses converged f) ----
    {
        float ie2 = LOG2E/C_EPS, neL = -C_EPS*LN2F;
        float r = ie2/prev_ie2;
        __syncthreads();
        for (int j=tid; j<ny; j+=1024) gs[j] = gl[j]*ie2;
        __syncthreads();
        float accf = 0.f;
        for (int i=w; i<nx; i+=16){
            const float* Cr = C + (size_t)i*ny;
            float mrow = mf[i]*r;
            float S = 0.f;
            for (int j=lane; j<ny; j+=64){
                float d = fmaf(Cr[j], -ie2, gs[j]) - mrow;
                S += ex2(fminf(d, 80.f));
            }
            #pragma unroll
            for (int o=32;o;o>>=1) S += __shfl_xor(S,o);
            if (lane==0) accf += neL*(mrow + lg2(S) - l2ny);
        }
        if (lane==0 && accf!=0.f) atomicAdd(&sacc[0], accf);
        __syncthreads();
        for (int i=tid; i<nx; i+=1024) gs[i] = fl[i]*ie2;
        __syncthreads();
        float accg = 0.f;
        for (int j=w; j<ny; j+=16){
            const float* Tr = CT + (size_t)j*nx;
            float mrow = mg[j]*r;
            float S = 0.f;
            for (int i=lane; i<nx; i+=64){
                float d = fmaf(Tr[i], -ie2, gs[i]) - mrow;
                S += ex2(fminf(d, 80.f));
            }
            #pragma unroll
            for (int o=32;o;o>>=1) S += __shfl_xor(S,o);
            if (lane==0) accg += neL*(mrow + lg2(S) - l2nx);
        }
        if (lane==0 && accg!=0.f) atomicAdd(&sacc[1], accg);
    }
    __syncthreads();
    if (tid==0){
        float wgt = (p%3==0) ? 1.f : -0.5f;
        atomicAdd(out, wgt*(sacc[0]/(float)nx + sacc[1]/(float)ny));
    }
}

extern "C" void kernel_launch(void* const* d_in, const int* in_sizes, int n_in,
                              void* d_out, int out_size, void* d_ws, size_t ws_size,
                              hipStream_t stream) {
    const float* x     = (const float*)d_in[0];
    const float* y     = (const float*)d_in[1];
    const float* cc    = (const float*)d_in[2];
    const float* ft    = (const float*)d_in[3];
    const int*   predt = (const int*)d_in[4];
    float* out = (float*)d_out;
    float* wf = (float*)d_ws;
    int*   wi = (int*)d_ws;

    hipMemsetAsync(d_ws, 0, 44*sizeof(int), stream);    // counters / maxes / fillings

    k_prep_x<<<12, 256, 0, stream>>>(x, cc, wf, wi);
    k_prep_y<<<12, 256, 0, stream>>>(y, predt, wf, wi);
    k_offsets<<<1, 64, 0, stream>>>(ft, wf, wi, out);   // writes out[0] = loss_fil + tables
    k_scatter<<<24, 256, 0, stream>>>(predt, wi);
    k_maxmat<<<dim3(48,48,3), 256, 0, stream>>>(x, y, wf, wi);
    k_gather<<<1024, 256, 0, stream>>>(x, y, wf, wi);

    k_sink<<<NPROB, 1024, 0, stream>>>(wf, wi, out);    // 1 block per OT problem, LDS-resident
}

// Round 8
// 4579.322 us; speedup vs baseline: 2.0895x; 2.0895x over previous
//
#include <hip/hip_runtime.h>
#include <hip/hip_bf16.h>
#include <float.h>

#define NN 3072
#define MM 3072
#define DD 64
#define KK 8
#define NPROB 24

constexpr float C_EPS   = 0.0025f;   // blur^2
constexpr int   C_NITER = 30;
constexpr float LOG2E = 1.4426950408889634f;
constexpr float LN2F  = 0.6931471805599453f;
constexpr float L2_SCAL2 = -0.6438561897747247f;   // log2(0.64)

__device__ __forceinline__ float ex2(float x){ return __builtin_amdgcn_exp2f(x); }
__device__ __forceinline__ float lg2(float x){ return __builtin_amdgcn_logf(x); }

// workspace layout in 4-byte units (identical to round 6, which passed bit-exact)
#define U_FILL 0        // 8 floats  (zeroed by memset)
#define U_MAXC 8        // 4 uints   (zeroed)
#define U_CNTX 12       // 8 int
#define U_CNTY 20       // 8 int
#define U_POSX 28       // 8 int
#define U_POSY 36       // 8 int  -> memset covers [0,44)
#define U_OFFX 44       // 9 int
#define U_OFFY 53       // 9 int
#define U_PNX  64       // 24 int
#define U_PNY  88
#define U_PRB  112
#define U_PCB  136
#define U_PRS  160
#define U_PCS  184
#define U_PCOFF 208     // 25 int
#define U_PTOF  233     // 24 int  (C^T offsets; == PCOFF for symmetric xx/yy)
#define U_TOFF  257     // 25 int
#define U_XSQ  320      // 3072 float
#define U_YSQ  3392     // 3072 float
#define U_PRED 6464     // 3072 int
#define U_ROWS 9536     // 3072 int
#define U_COLS 12608    // 3072 int
#define U_SUBC 15680    // compact submatrices C, then appended C^T blocks (floats)

// ---------------- kernel 1: per-x-point: norms, argmin, softmax filling ----------------
__global__ __launch_bounds__(256) void k_prep_x(const float* __restrict__ x,
                                                const float* __restrict__ cc,
                                                float* wf, int* wi) {
    __shared__ __align__(16) float c_s[KK][DD];
    __shared__ float csq_s[KK];
    __shared__ float fpart[KK];
    int tid = threadIdx.x;
    for (int e = tid; e < KK*DD; e += 256) c_s[e>>6][e&63] = cc[e];
    if (tid < KK) fpart[tid] = 0.f;
    __syncthreads();
    if (tid < KK) { float s=0.f; for (int d=0; d<DD; ++d){ float v=c_s[tid][d]; s+=v*v; } csq_s[tid]=s; }
    __syncthreads();
    int i = blockIdx.x*256 + tid;
    if (i < NN) {
        const float4* xr = (const float4*)(x + (size_t)i*DD);
        float4 xv[16];
        float xs = 0.f;
        #pragma unroll
        for (int q=0;q<16;++q){ xv[q]=xr[q];
            xs += xv[q].x*xv[q].x + xv[q].y*xv[q].y + xv[q].z*xv[q].z + xv[q].w*xv[q].w; }
        float dk[KK];
        #pragma unroll
        for (int k=0;k<KK;++k){
            const float4* cr = (const float4*)(&c_s[k][0]);
            float dot=0.f;
            #pragma unroll
            for (int q=0;q<16;++q){ float4 cv=cr[q];
                dot += xv[q].x*cv.x + xv[q].y*cv.y + xv[q].z*cv.z + xv[q].w*cv.w; }
            dk[k] = xs + csq_s[k] - 2.f*dot;
        }
        float dmin = dk[0]; int am=0;
        #pragma unroll
        for (int k=1;k<KK;++k){ if (dk[k] < dmin){ dmin=dk[k]; am=k; } }
        float se=0.f; float ek[KK];
        #pragma unroll
        for (int k=0;k<KK;++k){ ek[k] = ex2((dmin-dk[k])*LOG2E); se+=ek[k]; }
        float inv = 1.f/se;
        #pragma unroll
        for (int k=0;k<KK;++k) atomicAdd(&fpart[k], ek[k]*inv);
        wf[U_XSQ + i] = xs;
        wi[U_PRED + i] = am;
        atomicAdd(&wi[U_CNTX + am], 1);
    }
    __syncthreads();
    if (tid < KK) atomicAdd(&wf[U_FILL + tid], fpart[tid]);
}

// ---------------- kernel 2: per-target: norms + counts ----------------
__global__ __launch_bounds__(256) void k_prep_y(const float* __restrict__ y,
                                                const int* __restrict__ predt,
                                                float* wf, int* wi) {
    int j = blockIdx.x*256 + threadIdx.x;
    if (j < MM) {
        const float4* yr = (const float4*)(y + (size_t)j*DD);
        float s=0.f;
        #pragma unroll
        for (int q=0;q<16;++q){ float4 v=yr[q]; s += v.x*v.x+v.y*v.y+v.z*v.z+v.w*v.w; }
        wf[U_YSQ + j] = s;
        atomicAdd(&wi[U_CNTY + predt[j]], 1);
    }
}

// ---------------- kernel 3: prefix sums, problem tables, loss_fil ----------------
__global__ void k_offsets(const float* __restrict__ ftarg, float* wf, int* wi, float* out) {
    if (threadIdx.x != 0) return;
    int offx=0, offy=0;
    wi[U_OFFX]=0; wi[U_OFFY]=0;
    for (int k=0;k<KK;++k){
        offx += wi[U_CNTX+k]; wi[U_OFFX+k+1]=offx;
        offy += wi[U_CNTY+k]; wi[U_OFFY+k+1]=offy;
    }
    int co=0, to=0;
    for (int k=0;k<KK;++k){
        int cx=wi[U_CNTX+k], cy=wi[U_CNTY+k];
        bool val = (cx>0)&&(cy>0);
        for (int t=0;t<3;++t){
            int p=k*3+t;
            int nx = val ? (t==2?cy:cx) : 0;
            int ny = val ? (t==1?cx:cy) : 0;
            wi[U_PNX+p]=nx; wi[U_PNY+p]=ny;
            wi[U_PRB+p] = (t==2)? wi[U_OFFY+k] : wi[U_OFFX+k];
            wi[U_PCB+p] = (t==1)? wi[U_OFFX+k] : wi[U_OFFY+k];
            wi[U_PRS+p] = (t==2)?1:0;
            wi[U_PCS+p] = (t==1)?0:1;
            wi[U_PCOFF+p]=co; co += nx*ny;
            wi[U_TOFF+p]=to; to += ((nx+31)>>5)*((ny+31)>>5);
        }
    }
    wi[U_PCOFF+NPROB]=co; wi[U_TOFF+NPROB]=to;
    // C^T blocks appended after all C; xx/yy are symmetric so CT == C
    int cto = co;
    for (int p=0;p<NPROB;++p){
        if (p%3 == 0){ wi[U_PTOF+p] = cto; cto += wi[U_PNX+p]*wi[U_PNY+p]; }
        else         { wi[U_PTOF+p] = wi[U_PCOFF+p]; }
    }
    float lf=0.f;
    for (int k=0;k<KK;++k){ float fx = wf[U_FILL+k]/(float)NN; float dd = fx - ftarg[k]; lf += dd*dd; }
    out[0] = lf/(float)KK;
}

// ---------------- kernel 4: scatter compact index lists ----------------
__global__ __launch_bounds__(256) void k_scatter(const int* __restrict__ predt, int* wi) {
    int b = blockIdx.x;
    if (b < 12) {
        int i = b*256 + threadIdx.x;
        if (i < NN){ int k = wi[U_PRED+i]; int p = atomicAdd(&wi[U_POSX+k],1);
                     wi[U_ROWS + wi[U_OFFX+k] + p] = i; }
    } else {
        int j = (b-12)*256 + threadIdx.x;
        if (j < MM){ int k = predt[j]; int p = atomicAdd(&wi[U_POSY+k],1);
                     wi[U_COLS + wi[U_OFFY+k] + p] = j; }
    }
}

// ---------------- kernel 5: exact max over full cost matrices (tiled) ----------------
__global__ __launch_bounds__(256) void k_maxmat(const float* __restrict__ x,
                                                const float* __restrict__ y,
                                                float* wf, int* wi) {
    int z = blockIdx.z;
    const float* A = (z==2)? y : x;
    const float* B = (z==0)? y : ((z==1)? x : y);
    int aqo = (z==2)? U_YSQ : U_XSQ;
    int bqo = (z==1)? U_XSQ : U_YSQ;
    __shared__ float la[64][65];
    __shared__ float lb[64][65];
    __shared__ float laq[64], lbq[64];
    __shared__ float wred[4];
    int tid = threadIdx.x;
    int i0 = blockIdx.y*64, j0 = blockIdx.x*64;
    #pragma unroll
    for (int q=0;q<4;++q){
        int idx4 = tid + q*256;
        int r = idx4>>4; int c = (idx4&15)<<2;
        float4 va = *(const float4*)(A + (size_t)(i0+r)*DD + c);
        la[r][c]=va.x; la[r][c+1]=va.y; la[r][c+2]=va.z; la[r][c+3]=va.w;
        float4 vb = *(const float4*)(B + (size_t)(j0+r)*DD + c);
        lb[r][c]=vb.x; lb[r][c+1]=vb.y; lb[r][c+2]=vb.z; lb[r][c+3]=vb.w;
    }
    if (tid < 64) { laq[tid]=wf[aqo+i0+tid]; lbq[tid]=wf[bqo+j0+tid]; }
    __syncthreads();
    int r0 = (tid>>4)<<2, c0 = (tid&15)<<2;
    float acc[4][4] = {};
    for (int d=0; d<DD; ++d){
        float av[4], bv[4];
        #pragma unroll
        for (int a=0;a<4;++a){ av[a]=la[r0+a][d]; bv[a]=lb[c0+a][d]; }
        #pragma unroll
        for (int a=0;a<4;++a)
            #pragma unroll
            for (int b2=0;b2<4;++b2) acc[a][b2] += av[a]*bv[b2];
    }
    float m = 0.f;
    #pragma unroll
    for (int a=0;a<4;++a)
        #pragma unroll
        for (int b2=0;b2<4;++b2){
            float cst = 0.5f*(laq[r0+a]+lbq[c0+b2]) - acc[a][b2];
            m = fmaxf(m, cst);
        }
    #pragma unroll
    for (int o=32;o;o>>=1) m = fmaxf(m, __shfl_xor(m,o));
    int wid = tid>>6;
    if ((tid&63)==0) wred[wid]=m;
    __syncthreads();
    if (tid==0){
        float mm = fmaxf(fmaxf(wred[0],wred[1]),fmaxf(wred[2],wred[3]));
        atomicMax((unsigned int*)&wi[U_MAXC+z], __float_as_uint(mm));
    }
}

// ---------------- kernel 6: gather compact cost submatrices (+ C^T for xy) ----------------
__global__ __launch_bounds__(256) void k_gather(const float* __restrict__ x,
                                                const float* __restrict__ y,
                                                float* wf, int* wi) {
    __shared__ float xs_[32][65], ys_[32][65];
    __shared__ float cs_[32][33];
    __shared__ float rq[32], cq[32];
    __shared__ int toff_s[NPROB+1];
    int tid = threadIdx.x;
    if (tid <= NPROB) toff_s[tid] = wi[U_TOFF+tid];
    __syncthreads();
    int total = toff_s[NPROB];
    for (int tix = blockIdx.x; tix < total; tix += gridDim.x){
        int p = 0;
        while (toff_s[p+1] <= tix) ++p;
        int nx = wi[U_PNX+p], ny = wi[U_PNY+p];
        int tpr = (ny+31)>>5;
        int loc = tix - toff_s[p];
        int i0 = (loc/tpr)<<5, j0 = (loc%tpr)<<5;
        int rbase = wi[U_PRB+p], cbase = wi[U_PCB+p];
        int rs = wi[U_PRS+p], cs = wi[U_PCS+p];
        const float* rsrc = rs? y : x;
        const float* csrc = cs? y : x;
        const int* rlist = wi + (rs? U_COLS : U_ROWS);
        const int* clist = wi + (cs? U_COLS : U_ROWS);
        int rqo = rs? U_YSQ : U_XSQ;
        int cqo = cs? U_YSQ : U_XSQ;
        size_t coff = (size_t)wi[U_PCOFF+p];
        #pragma unroll
        for (int q=0;q<2;++q){
            int idx4 = tid + q*256;      // 0..511
            int r = idx4>>4, c = (idx4&15)<<2;
            if (i0 + r < nx){
                int gi = rlist[rbase + i0 + r];
                float4 v = *(const float4*)(rsrc + (size_t)gi*DD + c);
                xs_[r][c]=v.x; xs_[r][c+1]=v.y; xs_[r][c+2]=v.z; xs_[r][c+3]=v.w;
                if (c==0) rq[r] = wf[rqo + gi];
            }
            if (j0 + r < ny){
                int gj = clist[cbase + j0 + r];
                float4 v = *(const float4*)(csrc + (size_t)gj*DD + c);
                ys_[r][c]=v.x; ys_[r][c+1]=v.y; ys_[r][c+2]=v.z; ys_[r][c+3]=v.w;
                if (c==0) cq[r] = wf[cqo + gj];
            }
        }
        __syncthreads();
        int r = tid>>3, cb = (tid&7)<<2;
        float cv[4] = {0.f,0.f,0.f,0.f};
        if (i0 + r < nx){
            float acc[4] = {0.f,0.f,0.f,0.f};
            for (int d=0; d<DD; ++d){
                float xv = xs_[r][d];
                #pragma unroll
                for (int q=0;q<4;++q) acc[q] += xv*ys_[cb+q][d];
            }
            float* dst = wf + U_SUBC + coff + (size_t)(i0+r)*ny + j0;
            #pragma unroll
            for (int q=0;q<4;++q){
                int j = cb+q;
                cv[q] = 0.5f*(rq[r]+cq[j]) - acc[q];
                if (j0 + j < ny) dst[j] = cv[q];
            }
        }
        if (p%3 == 0){
            // stash tile, write transposed (coalesced along nx) into CT
            #pragma unroll
            for (int q=0;q<4;++q) cs_[r][cb+q] = cv[q];
            __syncthreads();
            if (j0 + r < ny){
                float* dT = wf + U_SUBC + (size_t)wi[U_PTOF+p] + (size_t)(j0+r)*nx + i0;
                #pragma unroll
                for (int q=0;q<4;++q){
                    int ii = cb+q;
                    if (i0 + ii < nx) dT[ii] = cs_[ii][r];
                }
            }
        }
        __syncthreads();
    }
}

// ---------------- sinkhorn sweep: EXACT chunked online-LSE, pipelined loads -------------
// Per wave: 2 rows in flight; per chunk a lane owns 4 strided columns (jb+lane+{0,64,128,192}).
// Loads for the NEXT chunk (8 global dwords + 4 LDS g-values) issue before processing the
// current chunk. Online merge uses the TRUE running max -> S >= 1 always, lg2(S) safe.
#define LD8C(JB, D00,D01,D02,D03,D10,D11,D12,D13, G0,G1,G2,G3) { \
    int ja=(JB)+lane, jb_=(JB)+lane+64, jc=(JB)+lane+128, jd=(JB)+lane+192; \
    D00 = (ja <ncols)? R0[ja]  : 0.f;  D01 = (jb_<ncols)? R0[jb_] : 0.f; \
    D02 = (jc <ncols)? R0[jc]  : 0.f;  D03 = (jd <ncols)? R0[jd]  : 0.f; \
    D10 = (ja <ncols)? R1[ja]  : 0.f;  D11 = (jb_<ncols)? R1[jb_] : 0.f; \
    D12 = (jc <ncols)? R1[jc]  : 0.f;  D13 = (jd <ncols)? R1[jd]  : 0.f; \
    G0  = (ja <ncols)? gs[ja]  : 0.f;  G1  = (jb_<ncols)? gs[jb_] : 0.f; \
    G2  = (jc <ncols)? gs[jc]  : 0.f;  G3  = (jd <ncols)? gs[jd]  : 0.f; \
}

#define PROCR(JB, D0,D1,D2,D3, G0,G1,G2,G3, M, S) { \
    int ja=(JB)+lane, jb_=(JB)+lane+64, jc=(JB)+lane+128, jd=(JB)+lane+192; \
    float t0 = (ja <ncols)? fmaf(D0, nie2, G0) : -3e38f; \
    float t1 = (jb_<ncols)? fmaf(D1, nie2, G1) : -3e38f; \
    float t2 = (jc <ncols)? fmaf(D2, nie2, G2) : -3e38f; \
    float t3 = (jd <ncols)? fmaf(D3, nie2, G3) : -3e38f; \
    float cm = fmaxf(fmaxf(t0,t1),fmaxf(t2,t3)); \
    float mn = fmaxf(M, cm); \
    float sm = ex2(t0-mn) + ex2(t1-mn) + ex2(t2-mn) + ex2(t3-mn); \
    S = fmaf(S, ex2(M-mn), sm); \
    M = mn; \
}

template<bool FIN>
__device__ __forceinline__ void sweep(const float* __restrict__ Cb, int ldc, int nrows, int ncols,
                                      const float* __restrict__ gs, float* __restrict__ pot,
                                      float ie2, float neL, float l2n, int w, int lane,
                                      float* saccSlot)
{
    float nie2 = -ie2;
    float acc = 0.f;
    for (int i0 = w*2; i0 < nrows; i0 += 32){
        int ia = i0;
        bool v1 = (i0+1 < nrows);
        int ib = v1 ? i0+1 : i0;
        const float* R0 = Cb + (size_t)ia*ldc;
        const float* R1 = Cb + (size_t)ib*ldc;
        float m0=-3e38f, m1=-3e38f, S0=0.f, S1=0.f;
        float a00,a01,a02,a03,a10,a11,a12,a13, ga0,ga1,ga2,ga3;
        LD8C(0, a00,a01,a02,a03,a10,a11,a12,a13, ga0,ga1,ga2,ga3)
        int jb = 0;
        for (; jb + 256 < ncols; jb += 256){
            float b00,b01,b02,b03,b10,b11,b12,b13, gb0,gb1,gb2,gb3;
            LD8C(jb+256, b00,b01,b02,b03,b10,b11,b12,b13, gb0,gb1,gb2,gb3)
            PROCR(jb, a00,a01,a02,a03, ga0,ga1,ga2,ga3, m0, S0)
            PROCR(jb, a10,a11,a12,a13, ga0,ga1,ga2,ga3, m1, S1)
            a00=b00; a01=b01; a02=b02; a03=b03;
            a10=b10; a11=b11; a12=b12; a13=b13;
            ga0=gb0; ga1=gb1; ga2=gb2; ga3=gb3;
        }
        PROCR(jb, a00,a01,a02,a03, ga0,ga1,ga2,ga3, m0, S0)
        PROCR(jb, a10,a11,a12,a13, ga0,ga1,ga2,ga3, m1, S1)
        // cross-lane exact LSE merge
        #pragma unroll
        for (int o=32;o;o>>=1){
            float mo=__shfl_xor(m0,o), So=__shfl_xor(S0,o);
            float mn=fmaxf(m0,mo); S0=fmaf(S0,ex2(m0-mn),So*ex2(mo-mn)); m0=mn;
            mo=__shfl_xor(m1,o); So=__shfl_xor(S1,o);
            mn=fmaxf(m1,mo); S1=fmaf(S1,ex2(m1-mn),So*ex2(mo-mn)); m1=mn;
        }
        if (lane==0){
            float v0  = neL*(m0 + lg2(S0) - l2n);
            float v1v = neL*(m1 + lg2(S1) - l2n);
            if (FIN){
                acc += v0;
                if (v1) acc += v1v;
            } else {
                pot[ia] = v0;
                if (v1) pot[ib] = v1v;
            }
        }
    }
    if (FIN && lane==0 && acc != 0.f) atomicAdd(saccSlot, acc);
}

// ---------------- kernel 7: one block per OT problem; whole sinkhorn in-block ----------------
__global__ __launch_bounds__(1024) void k_sink(float* wf, int* wi, float* out) {
    int p = blockIdx.x;
    int nx = wi[U_PNX+p], ny = wi[U_PNY+p];
    if (nx <= 0 || ny <= 0) return;
    int tid = threadIdx.x, w = tid>>6, lane = tid&63;
    float eps0 = fmaxf(__uint_as_float((unsigned)wi[U_MAXC + (p%3)]), C_EPS);
    const float* C  = wf + U_SUBC + (size_t)wi[U_PCOFF+p];
    const float* CT = wf + U_SUBC + (size_t)wi[U_PTOF+p];
    float l2ny = lg2((float)ny), l2nx = lg2((float)nx);
    __shared__ float fl[3072], gl[3072], gs[3072];
    __shared__ float sacc[2];
    for (int j=tid; j<ny; j+=1024) gl[j]=0.f;
    if (tid < 2) sacc[tid]=0.f;

    for (int it=0; it<C_NITER; ++it){
        float eps = fmaxf(eps0*ex2((float)it*L2_SCAL2), C_EPS);
        float ie2 = LOG2E/eps, neL = -eps*LN2F;
        __syncthreads();                        // gl stable / gs free
        for (int j=tid; j<ny; j+=1024) gs[j] = gl[j]*ie2;
        __syncthreads();
        sweep<false>(C, ny, nx, ny, gs, fl, ie2, neL, l2ny, w, lane, nullptr);
        __syncthreads();                        // fl stable / gs free
        for (int i=tid; i<nx; i+=1024) gs[i] = fl[i]*ie2;
        __syncthreads();
        sweep<false>(CT, nx, ny, nx, gs, gl, ie2, neL, l2nx, w, lane, nullptr);
    }
    // final differentiable update at eps=EPS: f2 (accumulate only), g2 (uses converged f)
    {
        float ie2 = LOG2E/C_EPS, neL = -C_EPS*LN2F;
        __syncthreads();
        for (int j=tid; j<ny; j+=1024) gs[j] = gl[j]*ie2;
        __syncthreads();
        sweep<true>(C, ny, nx, ny, gs, nullptr, ie2, neL, l2ny, w, lane, &sacc[0]);
        __syncthreads();
        for (int i=tid; i<nx; i+=1024) gs[i] = fl[i]*ie2;
        __syncthreads();
        sweep<true>(CT, nx, ny, nx, gs, nullptr, ie2, neL, l2nx, w, lane, &sacc[1]);
    }
    __syncthreads();
    if (tid==0){
        float wgt = (p%3==0) ? 1.f : -0.5f;
        atomicAdd(out, wgt*(sacc[0]/(float)nx + sacc[1]/(float)ny));
    }
}

extern "C" void kernel_launch(void* const* d_in, const int* in_sizes, int n_in,
                              void* d_out, int out_size, void* d_ws, size_t ws_size,
                              hipStream_t stream) {
    const float* x     = (const float*)d_in[0];
    const float* y     = (const float*)d_in[1];
    const float* cc    = (const float*)d_in[2];
    const float* ft    = (const float*)d_in[3];
    const int*   predt = (const int*)d_in[4];
    float* out = (float*)d_out;
    float* wf = (float*)d_ws;
    int*   wi = (int*)d_ws;

    hipMemsetAsync(d_ws, 0, 44*sizeof(int), stream);    // counters / maxes / fillings

    k_prep_x<<<12, 256, 0, stream>>>(x, cc, wf, wi);
    k_prep_y<<<12, 256, 0, stream>>>(y, predt, wf, wi);
    k_offsets<<<1, 64, 0, stream>>>(ft, wf, wi, out);   // writes out[0] = loss_fil + tables
    k_scatter<<<24, 256, 0, stream>>>(predt, wi);
    k_maxmat<<<dim3(48,48,3), 256, 0, stream>>>(x, y, wf, wi);
    k_gather<<<1024, 256, 0, stream>>>(x, y, wf, wi);

    k_sink<<<NPROB, 1024, 0, stream>>>(wf, wi, out);    // 1 block per OT problem, LDS-resident
}

// Round 9
// 916.890 us; speedup vs baseline: 10.4360x; 4.9944x over previous
//
#include <hip/hip_runtime.h>
#include <hip/hip_bf16.h>
#include <float.h>

#define NN 3072
#define MM 3072
#define DD 64
#define KK 8
#define NPROB 24

constexpr float C_EPS   = 0.0025f;   // blur^2
constexpr int   C_NITER = 30;
constexpr float LOG2E = 1.4426950408889634f;
constexpr float LN2F  = 0.6931471805599453f;
constexpr float L2_SCAL2 = -0.6438561897747247f;   // log2(0.64)

__device__ __forceinline__ float ex2(float x){ return __builtin_amdgcn_exp2f(x); }
__device__ __forceinline__ float lg2(float x){ return __builtin_amdgcn_logf(x); }

// workspace layout in 4-byte units
#define U_FILL 0        // 8 floats  (zeroed by memset)
#define U_MAXC 8        // 4 uints   (zeroed)
#define U_CNTX 12       // 8 int
#define U_CNTY 20       // 8 int
#define U_POSX 28       // 8 int
#define U_POSY 36       // 8 int  -> memset covers [0,44)
#define U_OFFX 44       // 9 int
#define U_OFFY 53       // 9 int
#define U_PNX  64       // 24 int
#define U_PNY  88
#define U_PRB  112
#define U_PCB  136
#define U_PRS  160
#define U_PCS  184
#define U_PCOFF 208     // 25 int
#define U_PTOF  233     // 24 int  (C^T offsets; == PCOFF for symmetric xx/yy)
#define U_TOFF  257     // 25 int
#define U_FTOF  288     // 25 int  (prefix of ceil(nx/32) f-tiles)
#define U_GTOF  313     // 25 int  (prefix of ceil(ny/32) g-tiles)
#define U_ACCF  344     // 24 float (zeroed in k_offsets)
#define U_ACCG  368     // 24 float
#define U_XSQ  400      // 3072 float
#define U_YSQ  3472     // 3072 float
#define U_PRED 6544     // 3072 int
#define U_ROWS 9616     // 3072 int
#define U_COLS 12688    // 3072 int
#define U_FPOT 15760    // 24*3072 float potentials f
#define U_GPOT 89488    // 24*3072 float potentials g (zeroed by memset)
#define U_SUBC 163216   // compact submatrices C, then appended C^T blocks (floats)

// ---------------- kernel 1: per-x-point: norms, argmin, softmax filling ----------------
__global__ __launch_bounds__(256) void k_prep_x(const float* __restrict__ x,
                                                const float* __restrict__ cc,
                                                float* wf, int* wi) {
    __shared__ __align__(16) float c_s[KK][DD];
    __shared__ float csq_s[KK];
    __shared__ float fpart[KK];
    int tid = threadIdx.x;
    for (int e = tid; e < KK*DD; e += 256) c_s[e>>6][e&63] = cc[e];
    if (tid < KK) fpart[tid] = 0.f;
    __syncthreads();
    if (tid < KK) { float s=0.f; for (int d=0; d<DD; ++d){ float v=c_s[tid][d]; s+=v*v; } csq_s[tid]=s; }
    __syncthreads();
    int i = blockIdx.x*256 + tid;
    if (i < NN) {
        const float4* xr = (const float4*)(x + (size_t)i*DD);
        float4 xv[16];
        float xs = 0.f;
        #pragma unroll
        for (int q=0;q<16;++q){ xv[q]=xr[q];
            xs += xv[q].x*xv[q].x + xv[q].y*xv[q].y + xv[q].z*xv[q].z + xv[q].w*xv[q].w; }
        float dk[KK];
        #pragma unroll
        for (int k=0;k<KK;++k){
            const float4* cr = (const float4*)(&c_s[k][0]);
            float dot=0.f;
            #pragma unroll
            for (int q=0;q<16;++q){ float4 cv=cr[q];
                dot += xv[q].x*cv.x + xv[q].y*cv.y + xv[q].z*cv.z + xv[q].w*cv.w; }
            dk[k] = xs + csq_s[k] - 2.f*dot;
        }
        float dmin = dk[0]; int am=0;
        #pragma unroll
        for (int k=1;k<KK;++k){ if (dk[k] < dmin){ dmin=dk[k]; am=k; } }
        float se=0.f; float ek[KK];
        #pragma unroll
        for (int k=0;k<KK;++k){ ek[k] = ex2((dmin-dk[k])*LOG2E); se+=ek[k]; }
        float inv = 1.f/se;
        #pragma unroll
        for (int k=0;k<KK;++k) atomicAdd(&fpart[k], ek[k]*inv);
        wf[U_XSQ + i] = xs;
        wi[U_PRED + i] = am;
        atomicAdd(&wi[U_CNTX + am], 1);
    }
    __syncthreads();
    if (tid < KK) atomicAdd(&wf[U_FILL + tid], fpart[tid]);
}

// ---------------- kernel 2: per-target: norms + counts ----------------
__global__ __launch_bounds__(256) void k_prep_y(const float* __restrict__ y,
                                                const int* __restrict__ predt,
                                                float* wf, int* wi) {
    int j = blockIdx.x*256 + threadIdx.x;
    if (j < MM) {
        const float4* yr = (const float4*)(y + (size_t)j*DD);
        float s=0.f;
        #pragma unroll
        for (int q=0;q<16;++q){ float4 v=yr[q]; s += v.x*v.x+v.y*v.y+v.z*v.z+v.w*v.w; }
        wf[U_YSQ + j] = s;
        atomicAdd(&wi[U_CNTY + predt[j]], 1);
    }
}

// ---------------- kernel 3: prefix sums, problem tables, loss_fil ----------------
__global__ void k_offsets(const float* __restrict__ ftarg, float* wf, int* wi, float* out) {
    if (threadIdx.x != 0) return;
    int offx=0, offy=0;
    wi[U_OFFX]=0; wi[U_OFFY]=0;
    for (int k=0;k<KK;++k){
        offx += wi[U_CNTX+k]; wi[U_OFFX+k+1]=offx;
        offy += wi[U_CNTY+k]; wi[U_OFFY+k+1]=offy;
    }
    int co=0, to=0, fo=0, go=0;
    for (int k=0;k<KK;++k){
        int cx=wi[U_CNTX+k], cy=wi[U_CNTY+k];
        bool val = (cx>0)&&(cy>0);
        for (int t=0;t<3;++t){
            int p=k*3+t;
            int nx = val ? (t==2?cy:cx) : 0;
            int ny = val ? (t==1?cx:cy) : 0;
            wi[U_PNX+p]=nx; wi[U_PNY+p]=ny;
            wi[U_PRB+p] = (t==2)? wi[U_OFFY+k] : wi[U_OFFX+k];
            wi[U_PCB+p] = (t==1)? wi[U_OFFX+k] : wi[U_OFFY+k];
            wi[U_PRS+p] = (t==2)?1:0;
            wi[U_PCS+p] = (t==1)?0:1;
            wi[U_PCOFF+p]=co; co += nx*ny;
            wi[U_TOFF+p]=to; to += ((nx+31)>>5)*((ny+31)>>5);
            wi[U_FTOF+p]=fo; fo += (nx+31)>>5;
            wi[U_GTOF+p]=go; go += (ny+31)>>5;
            wf[U_ACCF+p]=0.f; wf[U_ACCG+p]=0.f;
        }
    }
    wi[U_PCOFF+NPROB]=co; wi[U_TOFF+NPROB]=to;
    wi[U_FTOF+NPROB]=fo;  wi[U_GTOF+NPROB]=go;
    // C^T blocks appended after all C; xx/yy are symmetric so CT == C
    int cto = co;
    for (int p=0;p<NPROB;++p){
        if (p%3 == 0){ wi[U_PTOF+p] = cto; cto += wi[U_PNX+p]*wi[U_PNY+p]; }
        else         { wi[U_PTOF+p] = wi[U_PCOFF+p]; }
    }
    float lf=0.f;
    for (int k=0;k<KK;++k){ float fx = wf[U_FILL+k]/(float)NN; float dd = fx - ftarg[k]; lf += dd*dd; }
    out[0] = lf/(float)KK;
}

// ---------------- kernel 4: scatter compact index lists ----------------
__global__ __launch_bounds__(256) void k_scatter(const int* __restrict__ predt, int* wi) {
    int b = blockIdx.x;
    if (b < 12) {
        int i = b*256 + threadIdx.x;
        if (i < NN){ int k = wi[U_PRED+i]; int p = atomicAdd(&wi[U_POSX+k],1);
                     wi[U_ROWS + wi[U_OFFX+k] + p] = i; }
    } else {
        int j = (b-12)*256 + threadIdx.x;
        if (j < MM){ int k = predt[j]; int p = atomicAdd(&wi[U_POSY+k],1);
                     wi[U_COLS + wi[U_OFFY+k] + p] = j; }
    }
}

// ---------------- kernel 5: exact max over full cost matrices (tiled) ----------------
__global__ __launch_bounds__(256) void k_maxmat(const float* __restrict__ x,
                                                const float* __restrict__ y,
                                                float* wf, int* wi) {
    int z = blockIdx.z;
    const float* A = (z==2)? y : x;
    const float* B = (z==0)? y : ((z==1)? x : y);
    int aqo = (z==2)? U_YSQ : U_XSQ;
    int bqo = (z==1)? U_XSQ : U_YSQ;
    __shared__ float la[64][65];
    __shared__ float lb[64][65];
    __shared__ float laq[64], lbq[64];
    __shared__ float wred[4];
    int tid = threadIdx.x;
    int i0 = blockIdx.y*64, j0 = blockIdx.x*64;
    #pragma unroll
    for (int q=0;q<4;++q){
        int idx4 = tid + q*256;
        int r = idx4>>4; int c = (idx4&15)<<2;
        float4 va = *(const float4*)(A + (size_t)(i0+r)*DD + c);
        la[r][c]=va.x; la[r][c+1]=va.y; la[r][c+2]=va.z; la[r][c+3]=va.w;
        float4 vb = *(const float4*)(B + (size_t)(j0+r)*DD + c);
        lb[r][c]=vb.x; lb[r][c+1]=vb.y; lb[r][c+2]=vb.z; lb[r][c+3]=vb.w;
    }
    if (tid < 64) { laq[tid]=wf[aqo+i0+tid]; lbq[tid]=wf[bqo+j0+tid]; }
    __syncthreads();
    int r0 = (tid>>4)<<2, c0 = (tid&15)<<2;
    float acc[4][4] = {};
    for (int d=0; d<DD; ++d){
        float av[4], bv[4];
        #pragma unroll
        for (int a=0;a<4;++a){ av[a]=la[r0+a][d]; bv[a]=lb[c0+a][d]; }
        #pragma unroll
        for (int a=0;a<4;++a)
            #pragma unroll
            for (int b2=0;b2<4;++b2) acc[a][b2] += av[a]*bv[b2];
    }
    float m = 0.f;
    #pragma unroll
    for (int a=0;a<4;++a)
        #pragma unroll
        for (int b2=0;b2<4;++b2){
            float cst = 0.5f*(laq[r0+a]+lbq[c0+b2]) - acc[a][b2];
            m = fmaxf(m, cst);
        }
    #pragma unroll
    for (int o=32;o;o>>=1) m = fmaxf(m, __shfl_xor(m,o));
    int wid = tid>>6;
    if ((tid&63)==0) wred[wid]=m;
    __syncthreads();
    if (tid==0){
        float mm = fmaxf(fmaxf(wred[0],wred[1]),fmaxf(wred[2],wred[3]));
        atomicMax((unsigned int*)&wi[U_MAXC+z], __float_as_uint(mm));
    }
}

// ---------------- kernel 6: gather compact cost submatrices (+ C^T for xy) ----------------
__global__ __launch_bounds__(256) void k_gather(const float* __restrict__ x,
                                                const float* __restrict__ y,
                                                float* wf, int* wi) {
    __shared__ float xs_[32][65], ys_[32][65];
    __shared__ float cs_[32][33];
    __shared__ float rq[32], cq[32];
    __shared__ int toff_s[NPROB+1];
    int tid = threadIdx.x;
    if (tid <= NPROB) toff_s[tid] = wi[U_TOFF+tid];
    __syncthreads();
    int total = toff_s[NPROB];
    for (int tix = blockIdx.x; tix < total; tix += gridDim.x){
        int p = 0;
        while (toff_s[p+1] <= tix) ++p;
        int nx = wi[U_PNX+p], ny = wi[U_PNY+p];
        int tpr = (ny+31)>>5;
        int loc = tix - toff_s[p];
        int i0 = (loc/tpr)<<5, j0 = (loc%tpr)<<5;
        int rbase = wi[U_PRB+p], cbase = wi[U_PCB+p];
        int rs = wi[U_PRS+p], cs = wi[U_PCS+p];
        const float* rsrc = rs? y : x;
        const float* csrc = cs? y : x;
        const int* rlist = wi + (rs? U_COLS : U_ROWS);
        const int* clist = wi + (cs? U_COLS : U_ROWS);
        int rqo = rs? U_YSQ : U_XSQ;
        int cqo = cs? U_YSQ : U_XSQ;
        size_t coff = (size_t)wi[U_PCOFF+p];
        #pragma unroll
        for (int q=0;q<2;++q){
            int idx4 = tid + q*256;      // 0..511
            int r = idx4>>4, c = (idx4&15)<<2;
            if (i0 + r < nx){
                int gi = rlist[rbase + i0 + r];
                float4 v = *(const float4*)(rsrc + (size_t)gi*DD + c);
                xs_[r][c]=v.x; xs_[r][c+1]=v.y; xs_[r][c+2]=v.z; xs_[r][c+3]=v.w;
                if (c==0) rq[r] = wf[rqo + gi];
            }
            if (j0 + r < ny){
                int gj = clist[cbase + j0 + r];
                float4 v = *(const float4*)(csrc + (size_t)gj*DD + c);
                ys_[r][c]=v.x; ys_[r][c+1]=v.y; ys_[r][c+2]=v.z; ys_[r][c+3]=v.w;
                if (c==0) cq[r] = wf[cqo + gj];
            }
        }
        __syncthreads();
        int r = tid>>3, cb = (tid&7)<<2;
        float cv[4] = {0.f,0.f,0.f,0.f};
        if (i0 + r < nx){
            float acc[4] = {0.f,0.f,0.f,0.f};
            for (int d=0; d<DD; ++d){
                float xv = xs_[r][d];
                #pragma unroll
                for (int q=0;q<4;++q) acc[q] += xv*ys_[cb+q][d];
            }
            float* dst = wf + U_SUBC + coff + (size_t)(i0+r)*ny + j0;
            #pragma unroll
            for (int q=0;q<4;++q){
                int j = cb+q;
                cv[q] = 0.5f*(rq[r]+cq[j]) - acc[q];
                if (j0 + j < ny) dst[j] = cv[q];
            }
        }
        if (p%3 == 0){
            // stash tile, write transposed (coalesced along nx) into CT
            #pragma unroll
            for (int q=0;q<4;++q) cs_[r][cb+q] = cv[q];
            __syncthreads();
            if (j0 + r < ny){
                float* dT = wf + U_SUBC + (size_t)wi[U_PTOF+p] + (size_t)(j0+r)*nx + i0;
                #pragma unroll
                for (int q=0;q<4;++q){
                    int ii = cb+q;
                    if (i0 + ii < nx) dT[ii] = cs_[ii][r];
                }
            }
        }
        __syncthreads();
    }
}

// ---------------- sinkhorn sweep: EXACT chunked online-LSE, pipelined loads -------------
// Per wave: 2 rows in flight; per chunk a lane owns 4 strided columns (jb+lane+{0,64,128,192}).
// Loads for the NEXT chunk issue before processing the current chunk. Online merge uses the
// TRUE running max -> S >= 1 on real lanes, lg2(S) safe. (Bit-identical to round 8, passed.)
#define LD8C(JB, D00,D01,D02,D03,D10,D11,D12,D13, G0,G1,G2,G3) { \
    int ja=(JB)+lane, jb_=(JB)+lane+64, jc=(JB)+lane+128, jd=(JB)+lane+192; \
    D00 = (ja <ncols)? R0[ja]  : 0.f;  D01 = (jb_<ncols)? R0[jb_] : 0.f; \
    D02 = (jc <ncols)? R0[jc]  : 0.f;  D03 = (jd <ncols)? R0[jd]  : 0.f; \
    D10 = (ja <ncols)? R1[ja]  : 0.f;  D11 = (jb_<ncols)? R1[jb_] : 0.f; \
    D12 = (jc <ncols)? R1[jc]  : 0.f;  D13 = (jd <ncols)? R1[jd]  : 0.f; \
    G0  = (ja <ncols)? gs[ja]  : 0.f;  G1  = (jb_<ncols)? gs[jb_] : 0.f; \
    G2  = (jc <ncols)? gs[jc]  : 0.f;  G3  = (jd <ncols)? gs[jd]  : 0.f; \
}

#define PROCR(JB, D0,D1,D2,D3, G0,G1,G2,G3, M, S) { \
    int ja=(JB)+lane, jb_=(JB)+lane+64, jc=(JB)+lane+128, jd=(JB)+lane+192; \
    float t0 = (ja <ncols)? fmaf(D0, nie2, G0) : -3e38f; \
    float t1 = (jb_<ncols)? fmaf(D1, nie2, G1) : -3e38f; \
    float t2 = (jc <ncols)? fmaf(D2, nie2, G2) : -3e38f; \
    float t3 = (jd <ncols)? fmaf(D3, nie2, G3) : -3e38f; \
    float cm = fmaxf(fmaxf(t0,t1),fmaxf(t2,t3)); \
    float mn = fmaxf(M, cm); \
    float sm = ex2(t0-mn) + ex2(t1-mn) + ex2(t2-mn) + ex2(t3-mn); \
    S = fmaf(S, ex2(M-mn), sm); \
    M = mn; \
}

template<bool FIN>
__device__ __forceinline__ void sweep(const float* __restrict__ Cb, int ldc, int nrows, int ncols,
                                      const float* __restrict__ gs, float* __restrict__ pot,
                                      float ie2, float neL, float l2n, int w, int lane,
                                      float* saccSlot)
{
    float nie2 = -ie2;
    float acc = 0.f;
    for (int i0 = w*2; i0 < nrows; i0 += 32){
        int ia = i0;
        bool v1 = (i0+1 < nrows);
        int ib = v1 ? i0+1 : i0;
        const float* R0 = Cb + (size_t)ia*ldc;
        const float* R1 = Cb + (size_t)ib*ldc;
        float m0=-3e38f, m1=-3e38f, S0=0.f, S1=0.f;
        float a00,a01,a02,a03,a10,a11,a12,a13, ga0,ga1,ga2,ga3;
        LD8C(0, a00,a01,a02,a03,a10,a11,a12,a13, ga0,ga1,ga2,ga3)
        int jb = 0;
        for (; jb + 256 < ncols; jb += 256){
            float b00,b01,b02,b03,b10,b11,b12,b13, gb0,gb1,gb2,gb3;
            LD8C(jb+256, b00,b01,b02,b03,b10,b11,b12,b13, gb0,gb1,gb2,gb3)
            PROCR(jb, a00,a01,a02,a03, ga0,ga1,ga2,ga3, m0, S0)
            PROCR(jb, a10,a11,a12,a13, ga0,ga1,ga2,ga3, m1, S1)
            a00=b00; a01=b01; a02=b02; a03=b03;
            a10=b10; a11=b11; a12=b12; a13=b13;
            ga0=gb0; ga1=gb1; ga2=gb2; ga3=gb3;
        }
        PROCR(jb, a00,a01,a02,a03, ga0,ga1,ga2,ga3, m0, S0)
        PROCR(jb, a10,a11,a12,a13, ga0,ga1,ga2,ga3, m1, S1)
        // cross-lane exact LSE merge
        #pragma unroll
        for (int o=32;o;o>>=1){
            float mo=__shfl_xor(m0,o), So=__shfl_xor(S0,o);
            float mn=fmaxf(m0,mo); S0=fmaf(S0,ex2(m0-mn),So*ex2(mo-mn)); m0=mn;
            mo=__shfl_xor(m1,o); So=__shfl_xor(S1,o);
            mn=fmaxf(m1,mo); S1=fmaf(S1,ex2(m1-mn),So*ex2(mo-mn)); m1=mn;
        }
        if (lane==0){
            float v0  = neL*(m0 + lg2(S0) - l2n);
            float v1v = neL*(m1 + lg2(S1) - l2n);
            if (FIN){
                acc += v0;
                if (v1) acc += v1v;
            } else {
                pot[ia] = v0;
                if (v1) pot[ib] = v1v;
            }
        }
    }
    if (FIN && lane==0 && acc != 0.f) atomicAdd(saccSlot, acc);
}

// ---------------- kernel 7a: f-phase (launch per iteration; full-chip parallel) ----------
// One 32-row tile per block (16 waves x 2 rows); grid-stride over the FTOF tile space.
__global__ __launch_bounds__(1024) void k_f(float* wf, int* wi, int it, int fin) {
    __shared__ int toff[NPROB+1];
    __shared__ float gs[3072];
    int tid = threadIdx.x, w = tid>>6, lane = tid&63;
    if (tid <= NPROB) toff[tid] = wi[U_FTOF+tid];
    __syncthreads();
    int total = toff[NPROB];
    for (int tix = blockIdx.x; tix < total; tix += gridDim.x){
        int p = 0;
        while (toff[p+1] <= tix) ++p;
        int nx = wi[U_PNX+p], ny = wi[U_PNY+p];
        float eps0 = fmaxf(__uint_as_float((unsigned)wi[U_MAXC + (p%3)]), C_EPS);
        float eps = fin ? C_EPS : fmaxf(eps0*ex2((float)it*L2_SCAL2), C_EPS);
        float ie2 = LOG2E/eps, neL = -eps*LN2F;
        float l2n = lg2((float)ny);
        const float* C = wf + U_SUBC + (size_t)wi[U_PCOFF+p];
        const float* g = wf + U_GPOT + p*3072;
        __syncthreads();                       // previous tile done with gs
        for (int j=tid; j<ny; j+=1024) gs[j] = g[j]*ie2;
        __syncthreads();
        int rb = (tix - toff[p]) << 5;
        int cnt = min(32, nx - rb);
        if (!fin)
            sweep<false>(C + (size_t)rb*ny, ny, cnt, ny, gs,
                         wf + U_FPOT + p*3072 + rb, ie2, neL, l2n, w, lane, nullptr);
        else
            sweep<true>(C + (size_t)rb*ny, ny, cnt, ny, gs,
                        nullptr, ie2, neL, l2n, w, lane, &wf[U_ACCF+p]);
    }
}

// ---------------- kernel 7b: g-phase (reads CT rows = columns of C) ----------------
__global__ __launch_bounds__(1024) void k_g(float* wf, int* wi, int it, int fin) {
    __shared__ int toff[NPROB+1];
    __shared__ float gs[3072];
    int tid = threadIdx.x, w = tid>>6, lane = tid&63;
    if (tid <= NPROB) toff[tid] = wi[U_GTOF+tid];
    __syncthreads();
    int total = toff[NPROB];
    for (int tix = blockIdx.x; tix < total; tix += gridDim.x){
        int p = 0;
        while (toff[p+1] <= tix) ++p;
        int nx = wi[U_PNX+p], ny = wi[U_PNY+p];
        float eps0 = fmaxf(__uint_as_float((unsigned)wi[U_MAXC + (p%3)]), C_EPS);
        float eps = fin ? C_EPS : fmaxf(eps0*ex2((float)it*L2_SCAL2), C_EPS);
        float ie2 = LOG2E/eps, neL = -eps*LN2F;
        float l2n = lg2((float)nx);
        const float* CT = wf + U_SUBC + (size_t)wi[U_PTOF+p];
        const float* f = wf + U_FPOT + p*3072;
        __syncthreads();                       // previous tile done with gs
        for (int i=tid; i<nx; i+=1024) gs[i] = f[i]*ie2;
        __syncthreads();
        int rb = (tix - toff[p]) << 5;
        int cnt = min(32, ny - rb);
        if (!fin)
            sweep<false>(CT + (size_t)rb*nx, nx, cnt, nx, gs,
                         wf + U_GPOT + p*3072 + rb, ie2, neL, l2n, w, lane, nullptr);
        else
            sweep<true>(CT + (size_t)rb*nx, nx, cnt, nx, gs,
                        nullptr, ie2, neL, l2n, w, lane, &wf[U_ACCG+p]);
    }
}

// ---------------- kernel 8: finalize ----------------
__global__ void k_final(float* wf, int* wi, float* out) {
    if (threadIdx.x != 0 || blockIdx.x != 0) return;
    float s = 0.f;
    for (int p=0; p<NPROB; ++p){
        int nx = wi[U_PNX+p], ny = wi[U_PNY+p];
        if (nx<=0 || ny<=0) continue;
        float wgt = (p%3==0) ? 1.f : -0.5f;
        s += wgt * (wf[U_ACCF+p]/(float)nx + wf[U_ACCG+p]/(float)ny);
    }
    out[0] += s;
}

extern "C" void kernel_launch(void* const* d_in, const int* in_sizes, int n_in,
                              void* d_out, int out_size, void* d_ws, size_t ws_size,
                              hipStream_t stream) {
    const float* x     = (const float*)d_in[0];
    const float* y     = (const float*)d_in[1];
    const float* cc    = (const float*)d_in[2];
    const float* ft    = (const float*)d_in[3];
    const int*   predt = (const int*)d_in[4];
    float* out = (float*)d_out;
    float* wf = (float*)d_ws;
    int*   wi = (int*)d_ws;

    hipMemsetAsync(d_ws, 0, 44*sizeof(int), stream);                      // counters/maxes/fillings
    hipMemsetAsync(wf + U_GPOT, 0, NPROB*3072*sizeof(float), stream);     // g potentials start at 0

    k_prep_x<<<12, 256, 0, stream>>>(x, cc, wf, wi);
    k_prep_y<<<12, 256, 0, stream>>>(y, predt, wf, wi);
    k_offsets<<<1, 64, 0, stream>>>(ft, wf, wi, out);   // out[0] = loss_fil; tables; zero accs
    k_scatter<<<24, 256, 0, stream>>>(predt, wi);
    k_maxmat<<<dim3(48,48,3), 256, 0, stream>>>(x, y, wf, wi);
    k_gather<<<1024, 256, 0, stream>>>(x, y, wf, wi);

    for (int it = 0; it < C_NITER; ++it){
        k_f<<<320, 1024, 0, stream>>>(wf, wi, it, 0);
        k_g<<<320, 1024, 0, stream>>>(wf, wi, it, 0);
    }
    k_f<<<320, 1024, 0, stream>>>(wf, wi, C_NITER, 1);   // f2: accumulate into ACCF
    k_g<<<320, 1024, 0, stream>>>(wf, wi, C_NITER, 1);   // g2: uses converged f -> ACCG
    k_final<<<1, 64, 0, stream>>>(wf, wi, out);
}

// Round 10
// 771.211 us; speedup vs baseline: 12.4074x; 1.1889x over previous
//
#include <hip/hip_runtime.h>
#include <hip/hip_bf16.h>
#include <float.h>

#define NN 3072
#define MM 3072
#define DD 64
#define KK 8
#define NPROB 24
#define TPP 12            // blocks per problem team in persistent k_sink (24*12 = 288 blocks)

constexpr float C_EPS   = 0.0025f;   // blur^2
constexpr int   C_NITER = 30;
constexpr float LOG2E = 1.4426950408889634f;
constexpr float LN2F  = 0.6931471805599453f;
constexpr float L2_SCAL2 = -0.6438561897747247f;   // log2(0.64)

__device__ __forceinline__ float ex2(float x){ return __builtin_amdgcn_exp2f(x); }
__device__ __forceinline__ float lg2(float x){ return __builtin_amdgcn_logf(x); }

// system-scope relaxed ops: go to the die-level coherent LLC, NO cache invalidation.
__device__ __forceinline__ void  sst(float* p, float v){
    __hip_atomic_store(p, v, __ATOMIC_RELAXED, __HIP_MEMORY_SCOPE_SYSTEM);
}
__device__ __forceinline__ float sld(const float* p){
    return __hip_atomic_load((float*)p, __ATOMIC_RELAXED, __HIP_MEMORY_SCOPE_SYSTEM);
}

// workspace layout in 4-byte units
#define U_FILL 0        // 8 floats  (zeroed by memset)
#define U_MAXC 8        // 4 uints   (zeroed)
#define U_CNTX 12       // 8 int
#define U_CNTY 20       // 8 int
#define U_POSX 28       // 8 int
#define U_POSY 36       // 8 int  -> memset covers [0,44)
#define U_OFFX 44       // 9 int
#define U_OFFY 53       // 9 int
#define U_PNX  64       // 24 int
#define U_PNY  88
#define U_PRB  112
#define U_PCB  136
#define U_PRS  160
#define U_PCS  184
#define U_PCOFF 208     // 25 int
#define U_PTOF  233     // 24 int  (C^T offsets; == PCOFF for symmetric xx/yy)
#define U_TOFF  257     // 25 int
#define U_FTOF  288     // 25 int  (unused by k_sink; kept for table compat)
#define U_GTOF  313     // 25 int
#define U_ACCF  344     // 24 float (zeroed in k_offsets)
#define U_ACCG  368     // 24 float
#define U_BAR  400      // 24 teams x 64 ints: cnt at p*64, gen at p*64+32 (zeroed separately)
#define U_XSQ  1952     // 3072 float
#define U_YSQ  5024     // 3072 float
#define U_PRED 8096     // 3072 int
#define U_ROWS 11168    // 3072 int
#define U_COLS 14240    // 3072 int
#define U_FPOT 17312    // 24*3072 float potentials f
#define U_GPOT 91040    // 24*3072 float potentials g (zeroed by memset)
#define U_SUBC 164768   // compact submatrices C, then appended C^T blocks (floats)

// ---------------- kernel 1: per-x-point: norms, argmin, softmax filling ----------------
__global__ __launch_bounds__(256) void k_prep_x(const float* __restrict__ x,
                                                const float* __restrict__ cc,
                                                float* wf, int* wi) {
    __shared__ __align__(16) float c_s[KK][DD];
    __shared__ float csq_s[KK];
    __shared__ float fpart[KK];
    int tid = threadIdx.x;
    for (int e = tid; e < KK*DD; e += 256) c_s[e>>6][e&63] = cc[e];
    if (tid < KK) fpart[tid] = 0.f;
    __syncthreads();
    if (tid < KK) { float s=0.f; for (int d=0; d<DD; ++d){ float v=c_s[tid][d]; s+=v*v; } csq_s[tid]=s; }
    __syncthreads();
    int i = blockIdx.x*256 + tid;
    if (i < NN) {
        const float4* xr = (const float4*)(x + (size_t)i*DD);
        float4 xv[16];
        float xs = 0.f;
        #pragma unroll
        for (int q=0;q<16;++q){ xv[q]=xr[q];
            xs += xv[q].x*xv[q].x + xv[q].y*xv[q].y + xv[q].z*xv[q].z + xv[q].w*xv[q].w; }
        float dk[KK];
        #pragma unroll
        for (int k=0;k<KK;++k){
            const float4* cr = (const float4*)(&c_s[k][0]);
            float dot=0.f;
            #pragma unroll
            for (int q=0;q<16;++q){ float4 cv=cr[q];
                dot += xv[q].x*cv.x + xv[q].y*cv.y + xv[q].z*cv.z + xv[q].w*cv.w; }
            dk[k] = xs + csq_s[k] - 2.f*dot;
        }
        float dmin = dk[0]; int am=0;
        #pragma unroll
        for (int k=1;k<KK;++k){ if (dk[k] < dmin){ dmin=dk[k]; am=k; } }
        float se=0.f; float ek[KK];
        #pragma unroll
        for (int k=0;k<KK;++k){ ek[k] = ex2((dmin-dk[k])*LOG2E); se+=ek[k]; }
        float inv = 1.f/se;
        #pragma unroll
        for (int k=0;k<KK;++k) atomicAdd(&fpart[k], ek[k]*inv);
        wf[U_XSQ + i] = xs;
        wi[U_PRED + i] = am;
        atomicAdd(&wi[U_CNTX + am], 1);
    }
    __syncthreads();
    if (tid < KK) atomicAdd(&wf[U_FILL + tid], fpart[tid]);
}

// ---------------- kernel 2: per-target: norms + counts ----------------
__global__ __launch_bounds__(256) void k_prep_y(const float* __restrict__ y,
                                                const int* __restrict__ predt,
                                                float* wf, int* wi) {
    int j = blockIdx.x*256 + threadIdx.x;
    if (j < MM) {
        const float4* yr = (const float4*)(y + (size_t)j*DD);
        float s=0.f;
        #pragma unroll
        for (int q=0;q<16;++q){ float4 v=yr[q]; s += v.x*v.x+v.y*v.y+v.z*v.z+v.w*v.w; }
        wf[U_YSQ + j] = s;
        atomicAdd(&wi[U_CNTY + predt[j]], 1);
    }
}

// ---------------- kernel 3: prefix sums, problem tables, loss_fil ----------------
__global__ void k_offsets(const float* __restrict__ ftarg, float* wf, int* wi, float* out) {
    if (threadIdx.x != 0) return;
    int offx=0, offy=0;
    wi[U_OFFX]=0; wi[U_OFFY]=0;
    for (int k=0;k<KK;++k){
        offx += wi[U_CNTX+k]; wi[U_OFFX+k+1]=offx;
        offy += wi[U_CNTY+k]; wi[U_OFFY+k+1]=offy;
    }
    int co=0, to=0, fo=0, go=0;
    for (int k=0;k<KK;++k){
        int cx=wi[U_CNTX+k], cy=wi[U_CNTY+k];
        bool val = (cx>0)&&(cy>0);
        for (int t=0;t<3;++t){
            int p=k*3+t;
            int nx = val ? (t==2?cy:cx) : 0;
            int ny = val ? (t==1?cx:cy) : 0;
            wi[U_PNX+p]=nx; wi[U_PNY+p]=ny;
            wi[U_PRB+p] = (t==2)? wi[U_OFFY+k] : wi[U_OFFX+k];
            wi[U_PCB+p] = (t==1)? wi[U_OFFX+k] : wi[U_OFFY+k];
            wi[U_PRS+p] = (t==2)?1:0;
            wi[U_PCS+p] = (t==1)?0:1;
            wi[U_PCOFF+p]=co; co += nx*ny;
            wi[U_TOFF+p]=to; to += ((nx+31)>>5)*((ny+31)>>5);
            wi[U_FTOF+p]=fo; fo += (nx+31)>>5;
            wi[U_GTOF+p]=go; go += (ny+31)>>5;
            wf[U_ACCF+p]=0.f; wf[U_ACCG+p]=0.f;
        }
    }
    wi[U_PCOFF+NPROB]=co; wi[U_TOFF+NPROB]=to;
    wi[U_FTOF+NPROB]=fo;  wi[U_GTOF+NPROB]=go;
    // C^T blocks appended after all C; xx/yy are symmetric so CT == C
    int cto = co;
    for (int p=0;p<NPROB;++p){
        if (p%3 == 0){ wi[U_PTOF+p] = cto; cto += wi[U_PNX+p]*wi[U_PNY+p]; }
        else         { wi[U_PTOF+p] = wi[U_PCOFF+p]; }
    }
    float lf=0.f;
    for (int k=0;k<KK;++k){ float fx = wf[U_FILL+k]/(float)NN; float dd = fx - ftarg[k]; lf += dd*dd; }
    out[0] = lf/(float)KK;
}

// ---------------- kernel 4: scatter compact index lists ----------------
__global__ __launch_bounds__(256) void k_scatter(const int* __restrict__ predt, int* wi) {
    int b = blockIdx.x;
    if (b < 12) {
        int i = b*256 + threadIdx.x;
        if (i < NN){ int k = wi[U_PRED+i]; int p = atomicAdd(&wi[U_POSX+k],1);
                     wi[U_ROWS + wi[U_OFFX+k] + p] = i; }
    } else {
        int j = (b-12)*256 + threadIdx.x;
        if (j < MM){ int k = predt[j]; int p = atomicAdd(&wi[U_POSY+k],1);
                     wi[U_COLS + wi[U_OFFY+k] + p] = j; }
    }
}

// ---------------- kernel 5: exact max over full cost matrices (tiled) ----------------
__global__ __launch_bounds__(256) void k_maxmat(const float* __restrict__ x,
                                                const float* __restrict__ y,
                                                float* wf, int* wi) {
    int z = blockIdx.z;
    const float* A = (z==2)? y : x;
    const float* B = (z==0)? y : ((z==1)? x : y);
    int aqo = (z==2)? U_YSQ : U_XSQ;
    int bqo = (z==1)? U_XSQ : U_YSQ;
    __shared__ float la[64][65];
    __shared__ float lb[64][65];
    __shared__ float laq[64], lbq[64];
    __shared__ float wred[4];
    int tid = threadIdx.x;
    int i0 = blockIdx.y*64, j0 = blockIdx.x*64;
    #pragma unroll
    for (int q=0;q<4;++q){
        int idx4 = tid + q*256;
        int r = idx4>>4; int c = (idx4&15)<<2;
        float4 va = *(const float4*)(A + (size_t)(i0+r)*DD + c);
        la[r][c]=va.x; la[r][c+1]=va.y; la[r][c+2]=va.z; la[r][c+3]=va.w;
        float4 vb = *(const float4*)(B + (size_t)(j0+r)*DD + c);
        lb[r][c]=vb.x; lb[r][c+1]=vb.y; lb[r][c+2]=vb.z; lb[r][c+3]=vb.w;
    }
    if (tid < 64) { laq[tid]=wf[aqo+i0+tid]; lbq[tid]=wf[bqo+j0+tid]; }
    __syncthreads();
    int r0 = (tid>>4)<<2, c0 = (tid&15)<<2;
    float acc[4][4] = {};
    for (int d=0; d<DD; ++d){
        float av[4], bv[4];
        #pragma unroll
        for (int a=0;a<4;++a){ av[a]=la[r0+a][d]; bv[a]=lb[c0+a][d]; }
        #pragma unroll
        for (int a=0;a<4;++a)
            #pragma unroll
            for (int b2=0;b2<4;++b2) acc[a][b2] += av[a]*bv[b2];
    }
    float m = 0.f;
    #pragma unroll
    for (int a=0;a<4;++a)
        #pragma unroll
        for (int b2=0;b2<4;++b2){
            float cst = 0.5f*(laq[r0+a]+lbq[c0+b2]) - acc[a][b2];
            m = fmaxf(m, cst);
        }
    #pragma unroll
    for (int o=32;o;o>>=1) m = fmaxf(m, __shfl_xor(m,o));
    int wid = tid>>6;
    if ((tid&63)==0) wred[wid]=m;
    __syncthreads();
    if (tid==0){
        float mm = fmaxf(fmaxf(wred[0],wred[1]),fmaxf(wred[2],wred[3]));
        atomicMax((unsigned int*)&wi[U_MAXC+z], __float_as_uint(mm));
    }
}

// ---------------- kernel 6: gather compact cost submatrices (+ C^T for xy) ----------------
__global__ __launch_bounds__(256) void k_gather(const float* __restrict__ x,
                                                const float* __restrict__ y,
                                                float* wf, int* wi) {
    __shared__ float xs_[32][65], ys_[32][65];
    __shared__ float cs_[32][33];
    __shared__ float rq[32], cq[32];
    __shared__ int toff_s[NPROB+1];
    int tid = threadIdx.x;
    if (tid <= NPROB) toff_s[tid] = wi[U_TOFF+tid];
    __syncthreads();
    int total = toff_s[NPROB];
    for (int tix = blockIdx.x; tix < total; tix += gridDim.x){
        int p = 0;
        while (toff_s[p+1] <= tix) ++p;
        int nx = wi[U_PNX+p], ny = wi[U_PNY+p];
        int tpr = (ny+31)>>5;
        int loc = tix - toff_s[p];
        int i0 = (loc/tpr)<<5, j0 = (loc%tpr)<<5;
        int rbase = wi[U_PRB+p], cbase = wi[U_PCB+p];
        int rs = wi[U_PRS+p], cs = wi[U_PCS+p];
        const float* rsrc = rs? y : x;
        const float* csrc = cs? y : x;
        const int* rlist = wi + (rs? U_COLS : U_ROWS);
        const int* clist = wi + (cs? U_COLS : U_ROWS);
        int rqo = rs? U_YSQ : U_XSQ;
        int cqo = cs? U_YSQ : U_XSQ;
        size_t coff = (size_t)wi[U_PCOFF+p];
        #pragma unroll
        for (int q=0;q<2;++q){
            int idx4 = tid + q*256;      // 0..511
            int r = idx4>>4, c = (idx4&15)<<2;
            if (i0 + r < nx){
                int gi = rlist[rbase + i0 + r];
                float4 v = *(const float4*)(rsrc + (size_t)gi*DD + c);
                xs_[r][c]=v.x; xs_[r][c+1]=v.y; xs_[r][c+2]=v.z; xs_[r][c+3]=v.w;
                if (c==0) rq[r] = wf[rqo + gi];
            }
            if (j0 + r < ny){
                int gj = clist[cbase + j0 + r];
                float4 v = *(const float4*)(csrc + (size_t)gj*DD + c);
                ys_[r][c]=v.x; ys_[r][c+1]=v.y; ys_[r][c+2]=v.z; ys_[r][c+3]=v.w;
                if (c==0) cq[r] = wf[cqo + gj];
            }
        }
        __syncthreads();
        int r = tid>>3, cb = (tid&7)<<2;
        float cv[4] = {0.f,0.f,0.f,0.f};
        if (i0 + r < nx){
            float acc[4] = {0.f,0.f,0.f,0.f};
            for (int d=0; d<DD; ++d){
                float xv = xs_[r][d];
                #pragma unroll
                for (int q=0;q<4;++q) acc[q] += xv*ys_[cb+q][d];
            }
            float* dst = wf + U_SUBC + coff + (size_t)(i0+r)*ny + j0;
            #pragma unroll
            for (int q=0;q<4;++q){
                int j = cb+q;
                cv[q] = 0.5f*(rq[r]+cq[j]) - acc[q];
                if (j0 + j < ny) dst[j] = cv[q];
            }
        }
        if (p%3 == 0){
            // stash tile, write transposed (coalesced along nx) into CT
            #pragma unroll
            for (int q=0;q<4;++q) cs_[r][cb+q] = cv[q];
            __syncthreads();
            if (j0 + r < ny){
                float* dT = wf + U_SUBC + (size_t)wi[U_PTOF+p] + (size_t)(j0+r)*nx + i0;
                #pragma unroll
                for (int q=0;q<4;++q){
                    int ii = cb+q;
                    if (i0 + ii < nx) dT[ii] = cs_[ii][r];
                }
            }
        }
        __syncthreads();
    }
}

// ---------------- sinkhorn sweep: EXACT chunked online-LSE, pipelined loads -------------
// Per wave: 2 rows in flight; per chunk a lane owns 4 strided columns (jb+lane+{0,64,128,192}).
// Loads for the NEXT chunk issue before processing the current chunk. Online merge uses the
// TRUE running max -> S >= 1 on real lanes, lg2(S) safe. (Math bit-identical to r8/r9, passed.)
// Non-FIN potential writes go via system-scope relaxed stores (sst) -> visible at LLC without
// any cache invalidation (C/CT stay L2-resident across the whole persistent kernel).
#define LD8C(JB, D00,D01,D02,D03,D10,D11,D12,D13, G0,G1,G2,G3) { \
    int ja=(JB)+lane, jb_=(JB)+lane+64, jc=(JB)+lane+128, jd=(JB)+lane+192; \
    D00 = (ja <ncols)? R0[ja]  : 0.f;  D01 = (jb_<ncols)? R0[jb_] : 0.f; \
    D02 = (jc <ncols)? R0[jc]  : 0.f;  D03 = (jd <ncols)? R0[jd]  : 0.f; \
    D10 = (ja <ncols)? R1[ja]  : 0.f;  D11 = (jb_<ncols)? R1[jb_] : 0.f; \
    D12 = (jc <ncols)? R1[jc]  : 0.f;  D13 = (jd <ncols)? R1[jd]  : 0.f; \
    G0  = (ja <ncols)? gs[ja]  : 0.f;  G1  = (jb_<ncols)? gs[jb_] : 0.f; \
    G2  = (jc <ncols)? gs[jc]  : 0.f;  G3  = (jd <ncols)? gs[jd]  : 0.f; \
}

#define PROCR(JB, D0,D1,D2,D3, G0,G1,G2,G3, M, S) { \
    int ja=(JB)+lane, jb_=(JB)+lane+64, jc=(JB)+lane+128, jd=(JB)+lane+192; \
    float t0 = (ja <ncols)? fmaf(D0, nie2, G0) : -3e38f; \
    float t1 = (jb_<ncols)? fmaf(D1, nie2, G1) : -3e38f; \
    float t2 = (jc <ncols)? fmaf(D2, nie2, G2) : -3e38f; \
    float t3 = (jd <ncols)? fmaf(D3, nie2, G3) : -3e38f; \
    float cm = fmaxf(fmaxf(t0,t1),fmaxf(t2,t3)); \
    float mn = fmaxf(M, cm); \
    float sm = ex2(t0-mn) + ex2(t1-mn) + ex2(t2-mn) + ex2(t3-mn); \
    S = fmaf(S, ex2(M-mn), sm); \
    M = mn; \
}

template<bool FIN>
__device__ __forceinline__ void sweep(const float* __restrict__ Cb, int ldc, int nrows, int ncols,
                                      const float* __restrict__ gs, float* __restrict__ pot,
                                      float ie2, float neL, float l2n, int w, int lane,
                                      float* saccSlot)
{
    float nie2 = -ie2;
    float acc = 0.f;
    for (int i0 = w*2; i0 < nrows; i0 += 32){
        int ia = i0;
        bool v1 = (i0+1 < nrows);
        int ib = v1 ? i0+1 : i0;
        const float* R0 = Cb + (size_t)ia*ldc;
        const float* R1 = Cb + (size_t)ib*ldc;
        float m0=-3e38f, m1=-3e38f, S0=0.f, S1=0.f;
        float a00,a01,a02,a03,a10,a11,a12,a13, ga0,ga1,ga2,ga3;
        LD8C(0, a00,a01,a02,a03,a10,a11,a12,a13, ga0,ga1,ga2,ga3)
        int jb = 0;
        for (; jb + 256 < ncols; jb += 256){
            float b00,b01,b02,b03,b10,b11,b12,b13, gb0,gb1,gb2,gb3;
            LD8C(jb+256, b00,b01,b02,b03,b10,b11,b12,b13, gb0,gb1,gb2,gb3)
            PROCR(jb, a00,a01,a02,a03, ga0,ga1,ga2,ga3, m0, S0)
            PROCR(jb, a10,a11,a12,a13, ga0,ga1,ga2,ga3, m1, S1)
            a00=b00; a01=b01; a02=b02; a03=b03;
            a10=b10; a11=b11; a12=b12; a13=b13;
            ga0=gb0; ga1=gb1; ga2=gb2; ga3=gb3;
        }
        PROCR(jb, a00,a01,a02,a03, ga0,ga1,ga2,ga3, m0, S0)
        PROCR(jb, a10,a11,a12,a13, ga0,ga1,ga2,ga3, m1, S1)
        // cross-lane exact LSE merge
        #pragma unroll
        for (int o=32;o;o>>=1){
            float mo=__shfl_xor(m0,o), So=__shfl_xor(S0,o);
            float mn=fmaxf(m0,mo); S0=fmaf(S0,ex2(m0-mn),So*ex2(mo-mn)); m0=mn;
            mo=__shfl_xor(m1,o); So=__shfl_xor(S1,o);
            mn=fmaxf(m1,mo); S1=fmaf(S1,ex2(m1-mn),So*ex2(mo-mn)); m1=mn;
        }
        if (lane==0){
            float v0  = neL*(m0 + lg2(S0) - l2n);
            float v1v = neL*(m1 + lg2(S1) - l2n);
            if (FIN){
                acc += v0;
                if (v1) acc += v1v;
            } else {
                sst(&pot[ia], v0);
                if (v1) sst(&pot[ib], v1v);
            }
        }
    }
    if (FIN && lane==0 && acc != 0.f) atomicAdd(saccSlot, acc);
}

// ---------------- per-team barrier: RELAXED atomics only (no cache invalidation) --------
// __syncthreads() at entry drains each wave's vmcnt before s_barrier (compiler-guaranteed),
// so all sc0sc1 potential stores are complete at LLC before thread 0 signals arrival.
// Generation-based; cnt returns to 0 after each use -> graph-replay safe. Bounded spin
// failsafe: a logic bug yields a finite wrong run instead of a hung queue.
__device__ __forceinline__ void tbar(int* cnt, int* gen){
    __syncthreads();
    if (threadIdx.x == 0){
        asm volatile("s_waitcnt vmcnt(0)" ::: "memory");
        int g0 = __hip_atomic_load(gen, __ATOMIC_RELAXED, __HIP_MEMORY_SCOPE_AGENT);
        int a  = __hip_atomic_fetch_add(cnt, 1, __ATOMIC_RELAXED, __HIP_MEMORY_SCOPE_AGENT);
        if (a == TPP-1){
            __hip_atomic_store(cnt, 0, __ATOMIC_RELAXED, __HIP_MEMORY_SCOPE_AGENT);
            __hip_atomic_fetch_add(gen, 1, __ATOMIC_RELAXED, __HIP_MEMORY_SCOPE_AGENT);
        } else {
            int spins = 0;
            while (__hip_atomic_load(gen, __ATOMIC_RELAXED, __HIP_MEMORY_SCOPE_AGENT) == g0){
                __builtin_amdgcn_s_sleep(2);
                if (++spins > 100000) break;   // failsafe, never hit in correct runs
            }
        }
    }
    __syncthreads();
}

// ---------------- kernel 7: persistent sinkhorn — 12-block team per OT problem ----------
// grid = 288 blocks x 1024 threads (16 waves/block; 2 blocks/CU capacity -> all resident).
// C/CT reads are plain cached loads (L2-resident across all 31 iterations); only the
// potentials (~3KB/phase) cross blocks, via LLC (sst/sld). 2 relaxed barriers/iteration.
__global__ __launch_bounds__(1024) void k_sink(float* wf, int* wi, float* out) {
    int b  = blockIdx.x;
    int p  = b / TPP, sb = b % TPP;
    int nx = wi[U_PNX+p], ny = wi[U_PNY+p];
    if (nx <= 0 || ny <= 0) return;          // uniform across the team
    int tid = threadIdx.x, w = tid>>6, lane = tid&63;
    float eps0 = fmaxf(__uint_as_float((unsigned)wi[U_MAXC + (p%3)]), C_EPS);
    const float* C  = wf + U_SUBC + (size_t)wi[U_PCOFF+p];
    const float* CT = wf + U_SUBC + (size_t)wi[U_PTOF+p];
    float* f = wf + U_FPOT + p*3072;
    float* g = wf + U_GPOT + p*3072;
    float l2ny = lg2((float)ny), l2nx = lg2((float)nx);
    int* cnt = wi + U_BAR + p*64;
    int* gen = cnt + 32;
    int rb0 = (sb*nx)/TPP, re0 = ((sb+1)*nx)/TPP;   // this block's f-rows
    int cb0 = (sb*ny)/TPP, ce0 = ((sb+1)*ny)/TPP;   // this block's g-rows (CT rows)
    __shared__ float gs[3072];

    for (int it=0; it<C_NITER; ++it){
        float eps = fmaxf(eps0*ex2((float)it*L2_SCAL2), C_EPS);
        float ie2 = LOG2E/eps, neL = -eps*LN2F;
        // f-phase: stage g*ie2 (LLC loads), sweep own rows of C, store f via LLC
        for (int j=tid; j<ny; j+=1024) gs[j] = sld(g+j)*ie2;
        __syncthreads();
        sweep<false>(C + (size_t)rb0*ny, ny, re0-rb0, ny, gs, f+rb0, ie2, neL, l2ny, w, lane, nullptr);
        tbar(cnt, gen);
        // g-phase: stage f*ie2, sweep own rows of CT, store g via LLC
        for (int i=tid; i<nx; i+=1024) gs[i] = sld(f+i)*ie2;
        __syncthreads();
        sweep<false>(CT + (size_t)cb0*nx, nx, ce0-cb0, nx, gs, g+cb0, ie2, neL, l2nx, w, lane, nullptr);
        tbar(cnt, gen);
    }
    // final differentiable update at eps=EPS: f2 and g2 both read only converged f,g
    {
        float ie2 = LOG2E/C_EPS, neL = -C_EPS*LN2F;
        for (int j=tid; j<ny; j+=1024) gs[j] = sld(g+j)*ie2;
        __syncthreads();
        sweep<true>(C + (size_t)rb0*ny, ny, re0-rb0, ny, gs, nullptr, ie2, neL, l2ny, w, lane, &wf[U_ACCF+p]);
        __syncthreads();
        for (int i=tid; i<nx; i+=1024) gs[i] = sld(f+i)*ie2;
        __syncthreads();
        sweep<true>(CT + (size_t)cb0*nx, nx, ce0-cb0, nx, gs, nullptr, ie2, neL, l2nx, w, lane, &wf[U_ACCG+p]);
    }
}

// ---------------- kernel 8: finalize (separate launch -> no end-of-kernel sync needed) ---
__global__ void k_final(float* wf, int* wi, float* out) {
    if (threadIdx.x != 0 || blockIdx.x != 0) return;
    float s = 0.f;
    for (int p=0; p<NPROB; ++p){
        int nx = wi[U_PNX+p], ny = wi[U_PNY+p];
        if (nx<=0 || ny<=0) continue;
        float wgt = (p%3==0) ? 1.f : -0.5f;
        s += wgt * (wf[U_ACCF+p]/(float)nx + wf[U_ACCG+p]/(float)ny);
    }
    out[0] += s;
}

extern "C" void kernel_launch(void* const* d_in, const int* in_sizes, int n_in,
                              void* d_out, int out_size, void* d_ws, size_t ws_size,
                              hipStream_t stream) {
    const float* x     = (const float*)d_in[0];
    const float* y     = (const float*)d_in[1];
    const float* cc    = (const float*)d_in[2];
    const float* ft    = (const float*)d_in[3];
    const int*   predt = (const int*)d_in[4];
    float* out = (float*)d_out;
    float* wf = (float*)d_ws;
    int*   wi = (int*)d_ws;

    hipMemsetAsync(d_ws, 0, 44*sizeof(int), stream);                      // counters/maxes/fillings
    hipMemsetAsync(wi + U_BAR, 0, 24*64*sizeof(int), stream);             // team barriers
    hipMemsetAsync(wf + U_GPOT, 0, NPROB*3072*sizeof(float), stream);     // g potentials start at 0

    k_prep_x<<<12, 256, 0, stream>>>(x, cc, wf, wi);
    k_prep_y<<<12, 256, 0, stream>>>(y, predt, wf, wi);
    k_offsets<<<1, 64, 0, stream>>>(ft, wf, wi, out);   // out[0] = loss_fil; tables; zero accs
    k_scatter<<<24, 256, 0, stream>>>(predt, wi);
    k_maxmat<<<dim3(48,48,3), 256, 0, stream>>>(x, y, wf, wi);
    k_gather<<<1024, 256, 0, stream>>>(x, y, wf, wi);

    k_sink<<<NPROB*TPP, 1024, 0, stream>>>(wf, wi, out);   // persistent, fence-free teams
    k_final<<<1, 64, 0, stream>>>(wf, wi, out);
}

// Round 11
// 738.761 us; speedup vs baseline: 12.9524x; 1.0439x over previous
//
#include <hip/hip_runtime.h>
#include <hip/hip_bf16.h>
#include <float.h>

#define NN 3072
#define MM 3072
#define DD 64
#define KK 8
#define NPROB 24
#define NBLK 480          // persistent k_sink blocks (512 thr each; ~2/CU, balanced)

constexpr float C_EPS   = 0.0025f;   // blur^2
constexpr int   C_NITER = 30;
constexpr float LOG2E = 1.4426950408889634f;
constexpr float LN2F  = 0.6931471805599453f;
constexpr float L2_SCAL2 = -0.6438561897747247f;   // log2(0.64)

__device__ __forceinline__ float ex2(float x){ return __builtin_amdgcn_exp2f(x); }
__device__ __forceinline__ float lg2(float x){ return __builtin_amdgcn_logf(x); }

// system-scope relaxed ops: die-level coherent LLC, NO cache invalidation.
__device__ __forceinline__ void  sst(float* p, float v){
    __hip_atomic_store(p, v, __ATOMIC_RELAXED, __HIP_MEMORY_SCOPE_SYSTEM);
}
__device__ __forceinline__ float sld(const float* p){
    return __hip_atomic_load((float*)p, __ATOMIC_RELAXED, __HIP_MEMORY_SCOPE_SYSTEM);
}

// workspace layout in 4-byte units
#define U_FILL 0        // 8 floats  (zeroed by memset)
#define U_MAXC 8        // 4 uints   (zeroed)
#define U_CNTX 12       // 8 int
#define U_CNTY 20       // 8 int
#define U_POSX 28       // 8 int
#define U_POSY 36       // 8 int  -> memset covers [0,44)
#define U_OFFX 44       // 9 int
#define U_OFFY 53       // 9 int
#define U_PNX  64       // 24 int
#define U_PNY  88
#define U_PRB  112
#define U_PCB  136
#define U_PRS  160
#define U_PCS  184
#define U_PCOFF 208     // 25 int
#define U_PTOF  233     // 24 int  (C^T offsets; == PCOFF for symmetric xx/yy)
#define U_TOFF  257     // 25 int
#define U_ACCF  288     // 24 float (zeroed in k_offsets)
#define U_ACCG  312     // 24 float
#define U_TPPA  336     // 24 int team sizes
#define U_ASGN  384     // NBLK ints: (p<<16)|sb
#define U_BAR   896     // 24 teams x 64 ints: cnt at p*64, gen at p*64+32 (zeroed)
#define U_XSQ  2432     // 3072 float
#define U_YSQ  5504     // 3072 float
#define U_PRED 8576     // 3072 int
#define U_ROWS 11648    // 3072 int
#define U_COLS 14720    // 3072 int
#define U_FPOT 17792    // 24*3072 float potentials f
#define U_GPOT 91520    // 24*3072 float potentials g (zeroed by memset)
#define U_SUBC 165248   // compact submatrices C, then appended C^T blocks (floats)

// ---------------- kernel 1: merged prep (blocks 0-11: x side, 12-23: y side) -------------
__global__ __launch_bounds__(256) void k_prep(const float* __restrict__ x,
                                              const float* __restrict__ y,
                                              const float* __restrict__ cc,
                                              const int* __restrict__ predt,
                                              float* wf, int* wi) {
    int tid = threadIdx.x;
    if (blockIdx.x < 12) {
        __shared__ __align__(16) float c_s[KK][DD];
        __shared__ float csq_s[KK];
        __shared__ float fpart[KK];
        for (int e = tid; e < KK*DD; e += 256) c_s[e>>6][e&63] = cc[e];
        if (tid < KK) fpart[tid] = 0.f;
        __syncthreads();
        if (tid < KK) { float s=0.f; for (int d=0; d<DD; ++d){ float v=c_s[tid][d]; s+=v*v; } csq_s[tid]=s; }
        __syncthreads();
        int i = blockIdx.x*256 + tid;
        if (i < NN) {
            const float4* xr = (const float4*)(x + (size_t)i*DD);
            float4 xv[16];
            float xs = 0.f;
            #pragma unroll
            for (int q=0;q<16;++q){ xv[q]=xr[q];
                xs += xv[q].x*xv[q].x + xv[q].y*xv[q].y + xv[q].z*xv[q].z + xv[q].w*xv[q].w; }
            float dk[KK];
            #pragma unroll
            for (int k=0;k<KK;++k){
                const float4* cr = (const float4*)(&c_s[k][0]);
                float dot=0.f;
                #pragma unroll
                for (int q=0;q<16;++q){ float4 cv=cr[q];
                    dot += xv[q].x*cv.x + xv[q].y*cv.y + xv[q].z*cv.z + xv[q].w*cv.w; }
                dk[k] = xs + csq_s[k] - 2.f*dot;
            }
            float dmin = dk[0]; int am=0;
            #pragma unroll
            for (int k=1;k<KK;++k){ if (dk[k] < dmin){ dmin=dk[k]; am=k; } }
            float se=0.f; float ek[KK];
            #pragma unroll
            for (int k=0;k<KK;++k){ ek[k] = ex2((dmin-dk[k])*LOG2E); se+=ek[k]; }
            float inv = 1.f/se;
            #pragma unroll
            for (int k=0;k<KK;++k) atomicAdd(&fpart[k], ek[k]*inv);
            wf[U_XSQ + i] = xs;
            wi[U_PRED + i] = am;
            atomicAdd(&wi[U_CNTX + am], 1);
        }
        __syncthreads();
        if (tid < KK) atomicAdd(&wf[U_FILL + tid], fpart[tid]);
    } else {
        int j = (blockIdx.x-12)*256 + tid;
        if (j < MM) {
            const float4* yr = (const float4*)(y + (size_t)j*DD);
            float s=0.f;
            #pragma unroll
            for (int q=0;q<16;++q){ float4 v=yr[q]; s += v.x*v.x+v.y*v.y+v.z*v.z+v.w*v.w; }
            wf[U_YSQ + j] = s;
            atomicAdd(&wi[U_CNTY + predt[j]], 1);
        }
    }
}

// ---------------- kernel 3: prefix sums, tables, team allocation, loss_fil ----------------
__global__ void k_offsets(const float* __restrict__ ftarg, float* wf, int* wi, float* out) {
    if (threadIdx.x != 0) return;
    int offx=0, offy=0;
    wi[U_OFFX]=0; wi[U_OFFY]=0;
    for (int k=0;k<KK;++k){
        offx += wi[U_CNTX+k]; wi[U_OFFX+k+1]=offx;
        offy += wi[U_CNTY+k]; wi[U_OFFY+k+1]=offy;
    }
    int co=0, to=0;
    for (int k=0;k<KK;++k){
        int cx=wi[U_CNTX+k], cy=wi[U_CNTY+k];
        bool val = (cx>0)&&(cy>0);
        for (int t=0;t<3;++t){
            int p=k*3+t;
            int nx = val ? (t==2?cy:cx) : 0;
            int ny = val ? (t==1?cx:cy) : 0;
            wi[U_PNX+p]=nx; wi[U_PNY+p]=ny;
            wi[U_PRB+p] = (t==2)? wi[U_OFFY+k] : wi[U_OFFX+k];
            wi[U_PCB+p] = (t==1)? wi[U_OFFX+k] : wi[U_OFFY+k];
            wi[U_PRS+p] = (t==2)?1:0;
            wi[U_PCS+p] = (t==1)?0:1;
            wi[U_PCOFF+p]=co; co += nx*ny;
            wi[U_TOFF+p]=to; to += ((nx+31)>>5)*((ny+31)>>5);
            wf[U_ACCF+p]=0.f; wf[U_ACCG+p]=0.f;
        }
    }
    wi[U_PCOFF+NPROB]=co; wi[U_TOFF+NPROB]=to;
    // C^T blocks appended after all C; xx/yy are symmetric so CT == C
    int cto = co;
    for (int p=0;p<NPROB;++p){
        if (p%3 == 0){ wi[U_PTOF+p] = cto; cto += wi[U_PNX+p]*wi[U_PNY+p]; }
        else         { wi[U_PTOF+p] = wi[U_PCOFF+p]; }
    }
    // ---- work-proportional team allocation over NBLK blocks ----
    long long wsum = 0;
    int wk[NPROB], quota[NPROB], done[NPROB];
    for (int p=0;p<NPROB;++p){
        int nx=wi[U_PNX+p], ny=wi[U_PNY+p];
        wk[p] = (nx>0 && ny>0) ? nx*ny : 0;
        wsum += wk[p];
    }
    if (wsum == 0){
        for (int b=0;b<NBLK;++b) wi[U_ASGN+b] = (0xFF<<16);
        for (int p=0;p<NPROB;++p) wi[U_TPPA+p] = 0;
    } else {
        int tot=0;
        for (int p=0;p<NPROB;++p){
            quota[p] = (wk[p]>0) ? (int)(((long long)NBLK*wk[p])/wsum) : 0;
            if (wk[p]>0 && quota[p]<1) quota[p]=1;
            tot += quota[p];
        }
        while (tot < NBLK){
            int best=-1; float br=-1.f;
            for (int p=0;p<NPROB;++p) if (wk[p]>0){
                float r = (float)wk[p]/(float)quota[p];
                if (r>br){br=r;best=p;}
            }
            quota[best]++; tot++;
        }
        while (tot > NBLK){
            int best=-1; float br=3.4e38f;
            for (int p=0;p<NPROB;++p) if (quota[p]>1){
                float r = (float)wk[p]/(float)(quota[p]-1);
                if (r<br){br=r;best=p;}
            }
            if (best<0) break;
            quota[best]--; tot--;
        }
        for (int p=0;p<NPROB;++p){ done[p]=0; wi[U_TPPA+p]=quota[p]; }
        int asg=0;
        while (asg < NBLK){
            for (int p=0;p<NPROB && asg<NBLK;++p)
                if (done[p] < quota[p]){ wi[U_ASGN+asg] = (p<<16)|done[p]; done[p]++; asg++; }
        }
    }
    float lf=0.f;
    for (int k=0;k<KK;++k){ float fx = wf[U_FILL+k]/(float)NN; float dd = fx - ftarg[k]; lf += dd*dd; }
    out[0] = lf/(float)KK;
}

// ---------------- kernel 4: scatter compact index lists ----------------
__global__ __launch_bounds__(256) void k_scatter(const int* __restrict__ predt, int* wi) {
    int b = blockIdx.x;
    if (b < 12) {
        int i = b*256 + threadIdx.x;
        if (i < NN){ int k = wi[U_PRED+i]; int p = atomicAdd(&wi[U_POSX+k],1);
                     wi[U_ROWS + wi[U_OFFX+k] + p] = i; }
    } else {
        int j = (b-12)*256 + threadIdx.x;
        if (j < MM){ int k = predt[j]; int p = atomicAdd(&wi[U_POSY+k],1);
                     wi[U_COLS + wi[U_OFFY+k] + p] = j; }
    }
}

// ---------------- kernel 5: exact max over full cost matrices (tiled) ----------------
__global__ __launch_bounds__(256) void k_maxmat(const float* __restrict__ x,
                                                const float* __restrict__ y,
                                                float* wf, int* wi) {
    int z = blockIdx.z;
    const float* A = (z==2)? y : x;
    const float* B = (z==0)? y : ((z==1)? x : y);
    int aqo = (z==2)? U_YSQ : U_XSQ;
    int bqo = (z==1)? U_XSQ : U_YSQ;
    __shared__ float la[64][65];
    __shared__ float lb[64][65];
    __shared__ float laq[64], lbq[64];
    __shared__ float wred[4];
    int tid = threadIdx.x;
    int i0 = blockIdx.y*64, j0 = blockIdx.x*64;
    #pragma unroll
    for (int q=0;q<4;++q){
        int idx4 = tid + q*256;
        int r = idx4>>4; int c = (idx4&15)<<2;
        float4 va = *(const float4*)(A + (size_t)(i0+r)*DD + c);
        la[r][c]=va.x; la[r][c+1]=va.y; la[r][c+2]=va.z; la[r][c+3]=va.w;
        float4 vb = *(const float4*)(B + (size_t)(j0+r)*DD + c);
        lb[r][c]=vb.x; lb[r][c+1]=vb.y; lb[r][c+2]=vb.z; lb[r][c+3]=vb.w;
    }
    if (tid < 64) { laq[tid]=wf[aqo+i0+tid]; lbq[tid]=wf[bqo+j0+tid]; }
    __syncthreads();
    int r0 = (tid>>4)<<2, c0 = (tid&15)<<2;
    float acc[4][4] = {};
    for (int d=0; d<DD; ++d){
        float av[4], bv[4];
        #pragma unroll
        for (int a=0;a<4;++a){ av[a]=la[r0+a][d]; bv[a]=lb[c0+a][d]; }
        #pragma unroll
        for (int a=0;a<4;++a)
            #pragma unroll
            for (int b2=0;b2<4;++b2) acc[a][b2] += av[a]*bv[b2];
    }
    float m = 0.f;
    #pragma unroll
    for (int a=0;a<4;++a)
        #pragma unroll
        for (int b2=0;b2<4;++b2){
            float cst = 0.5f*(laq[r0+a]+lbq[c0+b2]) - acc[a][b2];
            m = fmaxf(m, cst);
        }
    #pragma unroll
    for (int o=32;o;o>>=1) m = fmaxf(m, __shfl_xor(m,o));
    int wid = tid>>6;
    if ((tid&63)==0) wred[wid]=m;
    __syncthreads();
    if (tid==0){
        float mm = fmaxf(fmaxf(wred[0],wred[1]),fmaxf(wred[2],wred[3]));
        atomicMax((unsigned int*)&wi[U_MAXC+z], __float_as_uint(mm));
    }
}

// ---------------- kernel 6: gather compact cost submatrices (+ C^T for xy) ----------------
__global__ __launch_bounds__(256) void k_gather(const float* __restrict__ x,
                                                const float* __restrict__ y,
                                                float* wf, int* wi) {
    __shared__ float xs_[32][65], ys_[32][65];
    __shared__ float cs_[32][33];
    __shared__ float rq[32], cq[32];
    __shared__ int toff_s[NPROB+1];
    int tid = threadIdx.x;
    if (tid <= NPROB) toff_s[tid] = wi[U_TOFF+tid];
    __syncthreads();
    int total = toff_s[NPROB];
    for (int tix = blockIdx.x; tix < total; tix += gridDim.x){
        int p = 0;
        while (toff_s[p+1] <= tix) ++p;
        int nx = wi[U_PNX+p], ny = wi[U_PNY+p];
        int tpr = (ny+31)>>5;
        int loc = tix - toff_s[p];
        int i0 = (loc/tpr)<<5, j0 = (loc%tpr)<<5;
        int rbase = wi[U_PRB+p], cbase = wi[U_PCB+p];
        int rs = wi[U_PRS+p], cs = wi[U_PCS+p];
        const float* rsrc = rs? y : x;
        const float* csrc = cs? y : x;
        const int* rlist = wi + (rs? U_COLS : U_ROWS);
        const int* clist = wi + (cs? U_COLS : U_ROWS);
        int rqo = rs? U_YSQ : U_XSQ;
        int cqo = cs? U_YSQ : U_XSQ;
        size_t coff = (size_t)wi[U_PCOFF+p];
        #pragma unroll
        for (int q=0;q<2;++q){
            int idx4 = tid + q*256;      // 0..511
            int r = idx4>>4, c = (idx4&15)<<2;
            if (i0 + r < nx){
                int gi = rlist[rbase + i0 + r];
                float4 v = *(const float4*)(rsrc + (size_t)gi*DD + c);
                xs_[r][c]=v.x; xs_[r][c+1]=v.y; xs_[r][c+2]=v.z; xs_[r][c+3]=v.w;
                if (c==0) rq[r] = wf[rqo + gi];
            }
            if (j0 + r < ny){
                int gj = clist[cbase + j0 + r];
                float4 v = *(const float4*)(csrc + (size_t)gj*DD + c);
                ys_[r][c]=v.x; ys_[r][c+1]=v.y; ys_[r][c+2]=v.z; ys_[r][c+3]=v.w;
                if (c==0) cq[r] = wf[cqo + gj];
            }
        }
        __syncthreads();
        int r = tid>>3, cb = (tid&7)<<2;
        float cv[4] = {0.f,0.f,0.f,0.f};
        if (i0 + r < nx){
            float acc[4] = {0.f,0.f,0.f,0.f};
            for (int d=0; d<DD; ++d){
                float xv = xs_[r][d];
                #pragma unroll
                for (int q=0;q<4;++q) acc[q] += xv*ys_[cb+q][d];
            }
            float* dst = wf + U_SUBC + coff + (size_t)(i0+r)*ny + j0;
            #pragma unroll
            for (int q=0;q<4;++q){
                int j = cb+q;
                cv[q] = 0.5f*(rq[r]+cq[j]) - acc[q];
                if (j0 + j < ny) dst[j] = cv[q];
            }
        }
        if (p%3 == 0){
            #pragma unroll
            for (int q=0;q<4;++q) cs_[r][cb+q] = cv[q];
            __syncthreads();
            if (j0 + r < ny){
                float* dT = wf + U_SUBC + (size_t)wi[U_PTOF+p] + (size_t)(j0+r)*nx + i0;
                #pragma unroll
                for (int q=0;q<4;++q){
                    int ii = cb+q;
                    if (i0 + ii < nx) dT[ii] = cs_[ii][r];
                }
            }
        }
        __syncthreads();
    }
}

// ---------------- sinkhorn sweep: exact online LSE; full chunks unchecked + masked tail ----
#define LD8F(JB, D00,D01,D02,D03,D10,D11,D12,D13, G0,G1,G2,G3) { \
    int ja=(JB)+lane; \
    D00=R0[ja]; D01=R0[ja+64]; D02=R0[ja+128]; D03=R0[ja+192]; \
    D10=R1[ja]; D11=R1[ja+64]; D12=R1[ja+128]; D13=R1[ja+192]; \
    G0=gs[ja];  G1=gs[ja+64];  G2=gs[ja+128];  G3=gs[ja+192]; }

#define PROCF(D0,D1,D2,D3, G0,G1,G2,G3, M, S) { \
    float t0=fmaf(D0,nie2,G0), t1=fmaf(D1,nie2,G1), t2=fmaf(D2,nie2,G2), t3=fmaf(D3,nie2,G3); \
    float cm = fmaxf(fmaxf(t0,t1),fmaxf(t2,t3)); \
    float mn = fmaxf(M, cm); \
    float sm = ex2(t0-mn) + ex2(t1-mn) + ex2(t2-mn) + ex2(t3-mn); \
    S = fmaf(S, ex2(M-mn), sm); \
    M = mn; }

#define LD8C(JB, D00,D01,D02,D03,D10,D11,D12,D13, G0,G1,G2,G3) { \
    int ja=(JB)+lane, jb_=(JB)+lane+64, jc=(JB)+lane+128, jd=(JB)+lane+192; \
    D00 = (ja <ncols)? R0[ja]  : 0.f;  D01 = (jb_<ncols)? R0[jb_] : 0.f; \
    D02 = (jc <ncols)? R0[jc]  : 0.f;  D03 = (jd <ncols)? R0[jd]  : 0.f; \
    D10 = (ja <ncols)? R1[ja]  : 0.f;  D11 = (jb_<ncols)? R1[jb_] : 0.f; \
    D12 = (jc <ncols)? R1[jc]  : 0.f;  D13 = (jd <ncols)? R1[jd]  : 0.f; \
    G0  = (ja <ncols)? gs[ja]  : 0.f;  G1  = (jb_<ncols)? gs[jb_] : 0.f; \
    G2  = (jc <ncols)? gs[jc]  : 0.f;  G3  = (jd <ncols)? gs[jd]  : 0.f; }

#define PROCR(JB, D0,D1,D2,D3, G0,G1,G2,G3, M, S) { \
    int ja=(JB)+lane, jb_=(JB)+lane+64, jc=(JB)+lane+128, jd=(JB)+lane+192; \
    float t0 = (ja <ncols)? fmaf(D0, nie2, G0) : -3e38f; \
    float t1 = (jb_<ncols)? fmaf(D1, nie2, G1) : -3e38f; \
    float t2 = (jc <ncols)? fmaf(D2, nie2, G2) : -3e38f; \
    float t3 = (jd <ncols)? fmaf(D3, nie2, G3) : -3e38f; \
    float cm = fmaxf(fmaxf(t0,t1),fmaxf(t2,t3)); \
    float mn = fmaxf(M, cm); \
    float sm = ex2(t0-mn) + ex2(t1-mn) + ex2(t2-mn) + ex2(t3-mn); \
    S = fmaf(S, ex2(M-mn), sm); \
    M = mn; }

template<bool FIN>
__device__ __forceinline__ void sweep(const float* __restrict__ Cb, int ldc, int nrows, int ncols,
                                      const float* __restrict__ gs, float* __restrict__ pot,
                                      float ie2, float neL, float l2n, int w, int lane,
                                      float* saccSlot)
{
    float nie2 = -ie2;
    float acc = 0.f;
    int nfull = ncols >> 8;
    int rem   = ncols & 255;
    for (int i0 = w*2; i0 < nrows; i0 += 16){        // 8 waves x 2 rows
        int ia = i0;
        bool v1 = (i0+1 < nrows);
        int ib = v1 ? i0+1 : i0;
        const float* R0 = Cb + (size_t)ia*ldc;
        const float* R1 = Cb + (size_t)ib*ldc;
        float m0=-3e38f, m1=-3e38f, S0=0.f, S1=0.f;
        if (nfull){
            float a00,a01,a02,a03,a10,a11,a12,a13, ga0,ga1,ga2,ga3;
            LD8F(0, a00,a01,a02,a03,a10,a11,a12,a13, ga0,ga1,ga2,ga3)
            for (int v=1; v<nfull; ++v){
                float b00,b01,b02,b03,b10,b11,b12,b13, gb0,gb1,gb2,gb3;
                LD8F(v<<8, b00,b01,b02,b03,b10,b11,b12,b13, gb0,gb1,gb2,gb3)
                PROCF(a00,a01,a02,a03, ga0,ga1,ga2,ga3, m0, S0)
                PROCF(a10,a11,a12,a13, ga0,ga1,ga2,ga3, m1, S1)
                a00=b00; a01=b01; a02=b02; a03=b03;
                a10=b10; a11=b11; a12=b12; a13=b13;
                ga0=gb0; ga1=gb1; ga2=gb2; ga3=gb3;
            }
            PROCF(a00,a01,a02,a03, ga0,ga1,ga2,ga3, m0, S0)
            PROCF(a10,a11,a12,a13, ga0,ga1,ga2,ga3, m1, S1)
        }
        if (rem){
            int jb = nfull<<8;
            float c00,c01,c02,c03,c10,c11,c12,c13, gc0,gc1,gc2,gc3;
            LD8C(jb, c00,c01,c02,c03,c10,c11,c12,c13, gc0,gc1,gc2,gc3)
            PROCR(jb, c00,c01,c02,c03, gc0,gc1,gc2,gc3, m0, S0)
            PROCR(jb, c10,c11,c12,c13, gc0,gc1,gc2,gc3, m1, S1)
        }
        // cross-lane exact LSE merge
        #pragma unroll
        for (int o=32;o;o>>=1){
            float mo=__shfl_xor(m0,o), So=__shfl_xor(S0,o);
            float mn=fmaxf(m0,mo); S0=fmaf(S0,ex2(m0-mn),So*ex2(mo-mn)); m0=mn;
            mo=__shfl_xor(m1,o); So=__shfl_xor(S1,o);
            mn=fmaxf(m1,mo); S1=fmaf(S1,ex2(m1-mn),So*ex2(mo-mn)); m1=mn;
        }
        if (lane==0){
            float v0  = neL*(m0 + lg2(S0) - l2n);
            float v1v = neL*(m1 + lg2(S1) - l2n);
            if (FIN){
                acc += v0;
                if (v1) acc += v1v;
            } else {
                sst(&pot[ia], v0);
                if (v1) sst(&pot[ib], v1v);
            }
        }
    }
    if (FIN && lane==0 && acc != 0.f) atomicAdd(saccSlot, acc);
}

// ---------------- per-team barrier: RELAXED atomics only (no cache invalidation) --------
__device__ __forceinline__ void tbar(int* cnt, int* gen, int tpp){
    __syncthreads();
    if (threadIdx.x == 0){
        asm volatile("s_waitcnt vmcnt(0)" ::: "memory");
        int g0 = __hip_atomic_load(gen, __ATOMIC_RELAXED, __HIP_MEMORY_SCOPE_AGENT);
        int a  = __hip_atomic_fetch_add(cnt, 1, __ATOMIC_RELAXED, __HIP_MEMORY_SCOPE_AGENT);
        if (a == tpp-1){
            __hip_atomic_store(cnt, 0, __ATOMIC_RELAXED, __HIP_MEMORY_SCOPE_AGENT);
            __hip_atomic_fetch_add(gen, 1, __ATOMIC_RELAXED, __HIP_MEMORY_SCOPE_AGENT);
        } else {
            int spins = 0;
            while (__hip_atomic_load(gen, __ATOMIC_RELAXED, __HIP_MEMORY_SCOPE_AGENT) == g0){
                __builtin_amdgcn_s_sleep(2);
                if (++spins > 200000) break;   // failsafe: finite wrong run, never a hang
            }
        }
    }
    __syncthreads();
}

// ---------------- kernel 7: persistent sinkhorn — work-proportional teams ----------------
// grid = NBLK x 512 threads. Team sizes from U_TPPA; block->(p,sb) from U_ASGN (interleaved
// so co-resident blocks belong to different teams -> barrier stalls overlap partner compute).
__global__ __launch_bounds__(512) void k_sink(float* wf, int* wi, float* out) {
    int av = wi[U_ASGN + blockIdx.x];
    int p  = av>>16, sb = av & 0xFFFF;
    if (p >= NPROB) return;
    int nx = wi[U_PNX+p], ny = wi[U_PNY+p];
    if (nx <= 0 || ny <= 0) return;
    int tpp = wi[U_TPPA+p];
    int tid = threadIdx.x, w = tid>>6, lane = tid&63;
    float eps0 = fmaxf(__uint_as_float((unsigned)wi[U_MAXC + (p%3)]), C_EPS);
    const float* C  = wf + U_SUBC + (size_t)wi[U_PCOFF+p];
    const float* CT = wf + U_SUBC + (size_t)wi[U_PTOF+p];
    float* f = wf + U_FPOT + p*3072;
    float* g = wf + U_GPOT + p*3072;
    float l2ny = lg2((float)ny), l2nx = lg2((float)nx);
    int* cnt = wi + U_BAR + p*64;
    int* gen = cnt + 32;
    int rb0 = (sb*nx)/tpp, re0 = ((sb+1)*nx)/tpp;   // this block's f-rows
    int cb0 = (sb*ny)/tpp, ce0 = ((sb+1)*ny)/tpp;   // this block's g-rows (CT rows)
    __shared__ float gs[3072];

    for (int it=0; it<C_NITER; ++it){
        float eps = fmaxf(eps0*ex2((float)it*L2_SCAL2), C_EPS);
        float ie2 = LOG2E/eps, neL = -eps*LN2F;
        for (int j=tid; j<ny; j+=512) gs[j] = sld(g+j)*ie2;
        __syncthreads();
        sweep<false>(C + (size_t)rb0*ny, ny, re0-rb0, ny, gs, f+rb0, ie2, neL, l2ny, w, lane, nullptr);
        tbar(cnt, gen, tpp);
        for (int i=tid; i<nx; i+=512) gs[i] = sld(f+i)*ie2;
        __syncthreads();
        sweep<false>(CT + (size_t)cb0*nx, nx, ce0-cb0, nx, gs, g+cb0, ie2, neL, l2nx, w, lane, nullptr);
        tbar(cnt, gen, tpp);
    }
    {
        float ie2 = LOG2E/C_EPS, neL = -C_EPS*LN2F;
        for (int j=tid; j<ny; j+=512) gs[j] = sld(g+j)*ie2;
        __syncthreads();
        sweep<true>(C + (size_t)rb0*ny, ny, re0-rb0, ny, gs, nullptr, ie2, neL, l2ny, w, lane, &wf[U_ACCF+p]);
        __syncthreads();
        for (int i=tid; i<nx; i+=512) gs[i] = sld(f+i)*ie2;
        __syncthreads();
        sweep<true>(CT + (size_t)cb0*nx, nx, ce0-cb0, nx, gs, nullptr, ie2, neL, l2nx, w, lane, &wf[U_ACCG+p]);
    }
}

// ---------------- kernel 8: finalize ----------------
__global__ void k_final(float* wf, int* wi, float* out) {
    if (threadIdx.x != 0 || blockIdx.x != 0) return;
    float s = 0.f;
    for (int p=0; p<NPROB; ++p){
        int nx = wi[U_PNX+p], ny = wi[U_PNY+p];
        if (nx<=0 || ny<=0) continue;
        float wgt = (p%3==0) ? 1.f : -0.5f;
        s += wgt * (wf[U_ACCF+p]/(float)nx + wf[U_ACCG+p]/(float)ny);
    }
    out[0] += s;
}

extern "C" void kernel_launch(void* const* d_in, const int* in_sizes, int n_in,
                              void* d_out, int out_size, void* d_ws, size_t ws_size,
                              hipStream_t stream) {
    const float* x     = (const float*)d_in[0];
    const float* y     = (const float*)d_in[1];
    const float* cc    = (const float*)d_in[2];
    const float* ft    = (const float*)d_in[3];
    const int*   predt = (const int*)d_in[4];
    float* out = (float*)d_out;
    float* wf = (float*)d_ws;
    int*   wi = (int*)d_ws;

    hipMemsetAsync(d_ws, 0, 44*sizeof(int), stream);                      // counters/maxes/fillings
    hipMemsetAsync(wi + U_BAR, 0, 24*64*sizeof(int), stream);             // team barriers
    hipMemsetAsync(wf + U_GPOT, 0, NPROB*3072*sizeof(float), stream);     // g potentials start at 0

    k_prep<<<24, 256, 0, stream>>>(x, y, cc, predt, wf, wi);
    k_offsets<<<1, 64, 0, stream>>>(ft, wf, wi, out);   // out[0]=loss_fil; tables; team alloc
    k_scatter<<<24, 256, 0, stream>>>(predt, wi);
    k_maxmat<<<dim3(48,48,3), 256, 0, stream>>>(x, y, wf, wi);
    k_gather<<<1024, 256, 0, stream>>>(x, y, wf, wi);

    k_sink<<<NBLK, 512, 0, stream>>>(wf, wi, out);      // persistent, fence-free teams
    k_final<<<1, 64, 0, stream>>>(wf, wi, out);
}